// Round 11
// baseline (361.483 us; speedup 1.0000x reference)
//
#include <hip/hip_runtime.h>
#include <hip/hip_fp16.h>

// Problem constants
static constexpr int NN   = 50000;
static constexpr int EE   = 800000;
static constexpr int GG   = 256;
static constexpr int BK   = 128;                // targets per bucket
static constexpr int NB   = (NN + BK - 1) / BK; // 391 buckets (bucket = dst>>7)
static constexpr int CAP  = 4096;               // bucket region capacity (mean 2048, sigma 45)
static constexpr int CH   = 2048;               // edges per binA block
static constexpr int ABLK = (EE + CH - 1) / CH; // 391
static constexpr int PBBB = EE / 64;            // 12500 ebuf2-build blocks piggybacked on aggh1

typedef _Float16 f16;
typedef f16  f16x8 __attribute__((ext_vector_type(8)));
typedef float f32x4 __attribute__((ext_vector_type(4)));

// ---------- fused prep: W1/W2 frag conversion + bcur init + pooled zeroing ----------
// frag (nt,ks,kq,m) = W^T[nt*16+m][ks*32+kq*8 .. +8)  at index ((nt*4+ks)*4+kq)*16+m
__global__ __launch_bounds__(256) void prep_k(const float* __restrict__ W1,
                                              const float* __restrict__ W2,
                                              f16x8* __restrict__ whi1, f16x8* __restrict__ wlo1,
                                              f16x8* __restrict__ whi2, f16x8* __restrict__ wlo2,
                                              int* __restrict__ bcur,
                                              float* __restrict__ pooled)
{
    int blk = blockIdx.x, t = threadIdx.x;
    if (blk < 16) {
        const float* W = (blk < 8) ? W1 : W2;
        f16x8* wh = (blk < 8) ? whi1 : whi2;
        f16x8* wl = (blk < 8) ? wlo1 : wlo2;
        int tid = (blk & 7) * 256 + t;      // 0..2047
        int m  = tid & 15;
        int kq = (tid >> 4) & 3;
        int ks = (tid >> 6) & 3;
        int nt = tid >> 8;
        int n  = nt * 16 + m;
        int k0 = ks * 32 + kq * 8;
        f16x8 h8, l8;
        #pragma unroll
        for (int u = 0; u < 8; u++) {
            float x = W[(size_t)(k0 + u) * 128 + n];
            f16 h = (f16)x;
            h8[u] = h;
            l8[u] = (f16)(x - (float)h);
        }
        wh[tid] = h8;
        wl[tid] = l8;
    } else if (blk == 16) {
        for (int b = t; b < NB; b += 256) bcur[b] = b * CAP;
    } else {
        float4* p = (float4*)pooled;        // GG*128 floats = 8192 float4
        for (int j = (blk - 17) * 256 + t; j < GG * 32; j += 512)
            p[j] = make_float4(0.f, 0.f, 0.f, 0.f);
    }
}

// Pass A: partition edges into fixed-capacity bucket regions, coalesced flush.
__global__ __launch_bounds__(512) void binA_k(const int* __restrict__ ei,
                                              int* __restrict__ bcur,
                                              int2* __restrict__ eraw)
{
    __shared__ int2  stage[CH];
    __shared__ short sbid[CH];
    __shared__ int   hist[NB], loff[NB], gbase[NB], lcur[NB];
    __shared__ int   sc[512];

    int tid = threadIdx.x;
    int e0 = blockIdx.x * CH;
    int n = EE - e0; if (n > CH) n = CH;

    for (int b = tid; b < NB; b += 512) hist[b] = 0;
    __syncthreads();

    int2 r[CH / 512];
    #pragma unroll
    for (int k = 0; k < CH / 512; k++) {
        int s = k * 512 + tid;
        if (s < n) {
            int src = ei[e0 + s];
            int dst = ei[EE + e0 + s];
            r[k] = make_int2(src, dst);
            atomicAdd(&hist[dst >> 7], 1);
        }
    }
    __syncthreads();
    int v = (tid < NB) ? hist[tid] : 0;
    sc[tid] = v;
    __syncthreads();
    #pragma unroll
    for (int off = 1; off < 512; off <<= 1) {
        int add = (tid >= off) ? sc[tid - off] : 0;
        __syncthreads();
        sc[tid] += add;
        __syncthreads();
    }
    if (tid < NB) { int ex = sc[tid] - v; loff[tid] = ex; lcur[tid] = ex; }
    __syncthreads();
    for (int b = tid; b < NB; b += 512)
        gbase[b] = atomicAdd(&bcur[b], hist[b]);
    __syncthreads();
    #pragma unroll
    for (int k = 0; k < CH / 512; k++) {
        int s = k * 512 + tid;
        if (s < n) {
            int b = r[k].y >> 7;
            int slot = atomicAdd(&lcur[b], 1);
            stage[slot] = r[k];
            sbid[slot]  = (short)b;
        }
    }
    __syncthreads();
    for (int s = tid; s < n; s += 512) {
        int b = sbid[s];
        eraw[(size_t)gbase[b] + (s - loff[b])] = stage[s];
    }
}

// scan bucket totals -> bucket base offsets; rowptr[NN]=EE
__global__ __launch_bounds__(512) void scanb2_k(const int* __restrict__ bcur,
                                                int* __restrict__ bbase,
                                                int* __restrict__ rowptr)
{
    __shared__ int s[512];
    int t = threadIdx.x;
    int v = (t < NB) ? (bcur[t] - t * CAP) : 0;
    s[t] = v;
    __syncthreads();
    #pragma unroll
    for (int off = 1; off < 512; off <<= 1) {
        int add = (t >= off) ? s[t - off] : 0;
        __syncthreads();
        s[t] += add;
        __syncthreads();
    }
    if (t < NB) bbase[t] = s[t] - v;
    if (t == 0) rowptr[NN] = EE;
}

// Pass B: per bucket: LDS hist -> rowptr + dinv, place src ints at exact CSR slots
__global__ __launch_bounds__(512) void binB_k(const int2* __restrict__ eraw,
                                              const int* __restrict__ bcur,
                                              const int* __restrict__ bbase,
                                              int* __restrict__ rowptr,
                                              float* __restrict__ dinv,
                                              int* __restrict__ ebuf)
{
    __shared__ int hist[BK], excl[BK], cur[BK];
    int b = blockIdx.x, tid = threadIdx.x;
    int t0 = b << 7;
    int lim = NN - t0; if (lim > BK) lim = BK;
    int tot  = bcur[b] - b * CAP;
    int base = bbase[b];
    const int2* er = eraw + (size_t)b * CAP;

    if (tid < BK) hist[tid] = 0;
    __syncthreads();
    for (int s = tid; s < tot; s += 512) atomicAdd(&hist[er[s].y & 127], 1);
    __syncthreads();
    if (tid < BK) excl[tid] = hist[tid];
    __syncthreads();
    #pragma unroll
    for (int off = 1; off < BK; off <<= 1) {
        int add = (tid >= off && tid < BK) ? excl[tid - off] : 0;
        __syncthreads();
        if (tid < BK) excl[tid] += add;
        __syncthreads();
    }
    if (tid < BK) {
        int ex = excl[tid] - hist[tid];
        cur[tid] = base + ex;
        if (tid < lim) {
            rowptr[t0 + tid] = base + ex;
            dinv[t0 + tid]   = rsqrtf((float)(hist[tid] + 1));   // deg + self-loop
        }
    }
    __syncthreads();
    for (int s = tid; s < tot; s += 512) {
        int2 rec = er[s];
        int p = atomicAdd(&cur[rec.y & 127], 1);
        ebuf[p] = rec.x;
    }
}

// ---------- MFMA GEMM: out = dinv .* (in @ W), fp16 out, split-precision ----------
// hi table staged in 32KB LDS; lo read from L2 (1 of 3 MFMAs).
// C/D: col=lane&15, row=(lane>>4)*4+reg (HW-verified).
__global__ __launch_bounds__(256) void gemm_mfma3_k(const float* __restrict__ in,
                                                    const f16x8* __restrict__ whi_f,
                                                    const f16x8* __restrict__ wlo_f,
                                                    const float* __restrict__ dinv,
                                                    __half* __restrict__ out,
                                                    int rows)
{
    __shared__ __align__(16) f16x8 sh[2048];    // 32KB: hi frags, same indexing as table
    int tid  = threadIdx.x;
    #pragma unroll
    for (int u = 0; u < 8; u++) sh[u * 256 + tid] = whi_f[u * 256 + tid];
    __syncthreads();

    int lane = tid & 63;
    int wv   = tid >> 6;
    int rB   = blockIdx.x * 64 + wv * 16;
    int m    = lane & 15;
    int kq   = lane >> 4;                  // 0..3
    int r    = rB + m;
    int rr   = (r < rows) ? r : (rows - 1);

    // A-frags: k = ks*32 + kq*8 + [0..8)
    f16x8 ahi[4], alo[4];
    const float* rp = in + (size_t)rr * 128 + kq * 8;
    #pragma unroll
    for (int ks = 0; ks < 4; ks++) {
        float4 p0 = *(const float4*)(rp + ks * 32);
        float4 p1 = *(const float4*)(rp + ks * 32 + 4);
        float xs[8] = {p0.x, p0.y, p0.z, p0.w, p1.x, p1.y, p1.z, p1.w};
        #pragma unroll
        for (int u = 0; u < 8; u++) {
            f16 h = (f16)xs[u];
            ahi[ks][u] = h;
            alo[ks][u] = (f16)(xs[u] - (float)h);
        }
    }

    f32x4 acc[8];
    #pragma unroll
    for (int n = 0; n < 8; n++) acc[n] = (f32x4){0.f, 0.f, 0.f, 0.f};

    #pragma unroll
    for (int nt = 0; nt < 8; nt++) {
        #pragma unroll
        for (int ks = 0; ks < 4; ks++) {
            int idx = ((nt * 4 + ks) * 4 + kq) * 16 + m;
            f16x8 bh = sh[idx];
            f16x8 bl = wlo_f[idx];
            acc[nt] = __builtin_amdgcn_mfma_f32_16x16x32_f16(ahi[ks], bh, acc[nt], 0, 0, 0);
            acc[nt] = __builtin_amdgcn_mfma_f32_16x16x32_f16(alo[ks], bh, acc[nt], 0, 0, 0);
            acc[nt] = __builtin_amdgcn_mfma_f32_16x16x32_f16(ahi[ks], bl, acc[nt], 0, 0, 0);
        }
    }

    // epilogue: row = kq*4 + reg, col = nt*16 + m; scale by dinv[row], store f16
    int   orow[4];
    float dv[4];
    #pragma unroll
    for (int j = 0; j < 4; j++) {
        int gr = rB + kq * 4 + j;
        orow[j] = gr;
        dv[j]   = (gr < rows) ? dinv[gr] : 0.f;
    }
    #pragma unroll
    for (int nt = 0; nt < 8; nt++) {
        int c = nt * 16 + m;
        #pragma unroll
        for (int j = 0; j < 4; j++) {
            if (orow[j] < rows)
                out[(size_t)orow[j] * 128 + c] = __float2half(acc[nt][j] * dv[j]);
        }
    }
}

// ---------- aggregation gather body (PROVEN r8 version) ----------
__device__ __forceinline__ float4 gat4h(const __half* __restrict__ t, int s, int q)
{
    uint2 v = *(const uint2*)(t + ((size_t)s << 7) + q * 4);
    __half2 a = __builtin_bit_cast(__half2, v.x);
    __half2 b = __builtin_bit_cast(__half2, v.y);
    float2 fa = __half22float2(a), fb = __half22float2(b);
    return make_float4(fa.x, fa.y, fb.x, fb.y);
}

// core: accumulate sum_e t[src_e][q*4..q*4+4) + t[i][...] into a0..a3 (halves folded)
#define AGG_BODY                                                                 \
    int e0 = __builtin_amdgcn_readfirstlane(rowptr[i]);                          \
    int e1 = __builtin_amdgcn_readfirstlane(rowptr[i + 1]);                      \
    int deg = e1 - e0;                                                           \
    int idxsafe = (deg > 0) ? (e0 + min(lane, deg - 1)) : 0;                     \
    int myidx = ebuf[idxsafe];                                                   \
    float a0 = 0.f, a1 = 0.f, a2 = 0.f, a3 = 0.f;                                \
    if (half == 0) {                                                             \
        float4 v = gat4h(t, i, q);                                               \
        a0 = v.x; a1 = v.y; a2 = v.z; a3 = v.w;                                  \
    }                                                                            \
    int v   = min(deg, 64);                                                      \
    int c16 = v & ~15;                                                           \
    for (int j = half * 8; j < c16; j += 16) {                                   \
        int s0 = __shfl(myidx, j + 0), s1 = __shfl(myidx, j + 1);                \
        int s2 = __shfl(myidx, j + 2), s3 = __shfl(myidx, j + 3);                \
        int s4 = __shfl(myidx, j + 4), s5 = __shfl(myidx, j + 5);                \
        int s6 = __shfl(myidx, j + 6), s7 = __shfl(myidx, j + 7);                \
        float4 w0 = gat4h(t, s0, q);                                             \
        float4 w1 = gat4h(t, s1, q);                                             \
        float4 w2 = gat4h(t, s2, q);                                             \
        float4 w3 = gat4h(t, s3, q);                                             \
        float4 w4 = gat4h(t, s4, q);                                             \
        float4 w5 = gat4h(t, s5, q);                                             \
        float4 w6 = gat4h(t, s6, q);                                             \
        float4 w7 = gat4h(t, s7, q);                                             \
        a0 += w0.x + w1.x + w2.x + w3.x + w4.x + w5.x + w6.x + w7.x;             \
        a1 += w0.y + w1.y + w2.y + w3.y + w4.y + w5.y + w6.y + w7.y;             \
        a2 += w0.z + w1.z + w2.z + w3.z + w4.z + w5.z + w6.z + w7.z;             \
        a3 += w0.w + w1.w + w2.w + w3.w + w4.w + w5.w + w6.w + w7.w;             \
    }                                                                            \
    if (v - c16 >= 8) {                                                          \
        int j = c16 + half * 4;                                                  \
        int s0 = __shfl(myidx, j + 0), s1 = __shfl(myidx, j + 1);                \
        int s2 = __shfl(myidx, j + 2), s3 = __shfl(myidx, j + 3);                \
        float4 w0 = gat4h(t, s0, q);                                             \
        float4 w1 = gat4h(t, s1, q);                                             \
        float4 w2 = gat4h(t, s2, q);                                             \
        float4 w3 = gat4h(t, s3, q);                                             \
        a0 += w0.x + w1.x + w2.x + w3.x;                                         \
        a1 += w0.y + w1.y + w2.y + w3.y;                                         \
        a2 += w0.z + w1.z + w2.z + w3.z;                                         \
        a3 += w0.w + w1.w + w2.w + w3.w;                                         \
    }                                                                            \
    int done = c16 + ((v - c16) & 8);                                            \
    for (int j = done + half; j < v; j += 2) {                                   \
        int s = __shfl(myidx, j);                                                \
        float4 w = gat4h(t, s, q);                                               \
        a0 += w.x; a1 += w.y; a2 += w.z; a3 += w.w;                              \
    }                                                                            \
    for (int e = e0 + 64 + half; e < e1; e += 2) {                               \
        float4 w = gat4h(t, ebuf[e], q);                                         \
        a0 += w.x; a1 += w.y; a2 += w.z; a3 += w.w;                              \
    }                                                                            \
    a0 += __shfl_xor(a0, 32);                                                    \
    a1 += __shfl_xor(a1, 32);                                                    \
    a2 += __shfl_xor(a2, 32);                                                    \
    a3 += __shfl_xor(a3, 32);

// conv1 aggregation -> writes h1 rows; blocks >= NN piggyback the ebuf2 build
__global__ __launch_bounds__(64) void aggh_k(const __half* __restrict__ t,
                                             const int* __restrict__ rowptr,
                                             const int* __restrict__ ebuf,
                                             const float* __restrict__ dinv,
                                             const float* __restrict__ bias,
                                             float* __restrict__ out,
                                             const int* __restrict__ batch,
                                             int2* __restrict__ ebuf2)
{
    int bid  = blockIdx.x;
    int lane = threadIdx.x;
    if (bid >= NN) {                      // piggybacked ebuf2 build: 64 edges/block
        int e = (bid - NN) * 64 + lane;
        if (e < EE) {
            int src = ebuf[e];
            ebuf2[e] = make_int2(batch[src], __float_as_int(dinv[src]));
        }
        return;
    }
    int i    = bid;
    int half = lane >> 5;
    int q    = lane & 31;
    AGG_BODY
    if (half == 0) {
        float di = dinv[i];
        float4 b = *(const float4*)(bias + q * 4);
        float4 o;
        o.x = fmaxf(di * a0 + b.x, 0.f);
        o.y = fmaxf(di * a1 + b.y, 0.f);
        o.z = fmaxf(di * a2 + b.z, 0.f);
        o.w = fmaxf(di * a3 + b.w, 0.f);
        *(float4*)(out + (size_t)i * 128 + q * 4) = o;
    }
}

// conv2 aggregation fused with global_add_pool: h2 row goes straight into pooled[batch[i]]
// (h2 is consumed ONLY by pooling -> skip the 25.6MB B write + pool2's 25.6MB re-read)
__global__ __launch_bounds__(64) void aggh_pool_k(const __half* __restrict__ t,
                                                  const int* __restrict__ rowptr,
                                                  const int* __restrict__ ebuf,
                                                  const float* __restrict__ dinv,
                                                  const float* __restrict__ bias,
                                                  const int* __restrict__ batch,
                                                  float* __restrict__ pooled)
{
    int i    = blockIdx.x;
    int lane = threadIdx.x;
    int half = lane >> 5;
    int q    = lane & 31;
    AGG_BODY
    if (half == 0) {
        float di = dinv[i];
        float4 b = *(const float4*)(bias + q * 4);
        float ox = fmaxf(di * a0 + b.x, 0.f);
        float oy = fmaxf(di * a1 + b.y, 0.f);
        float oz = fmaxf(di * a2 + b.z, 0.f);
        float ow = fmaxf(di * a3 + b.w, 0.f);
        float* pp = pooled + (size_t)batch[i] * 128 + q * 4;
        atomicAdd(pp + 0, ox);
        atomicAdd(pp + 1, oy);
        atomicAdd(pp + 2, oz);
        atomicAdd(pp + 3, ow);
    }
}

// conv3 aggregation, paired-edge (PROVEN r8 version): ebuf2 = {bg, w=dinv[src]};
// zz (131KB) L2-resident. Lane covers float4; halves process alternate edge-chunks.
__global__ __launch_bounds__(64) void agg_out_k(const float* __restrict__ zz,
                                                const int* __restrict__ batch,
                                                const int* __restrict__ rowptr,
                                                const int2* __restrict__ ebuf2,
                                                const float* __restrict__ dinv,
                                                const float* __restrict__ bias,
                                                float* __restrict__ out)
{
    int i    = blockIdx.x;
    int lane = threadIdx.x;
    int half = lane >> 5;
    int q    = lane & 31;
    float di = dinv[i];

    float a0 = 0.f, a1 = 0.f, a2 = 0.f, a3 = 0.f;
    if (half == 0) {                     // self term: di * zz[batch[i]]
        float4 v = *(const float4*)(zz + ((size_t)batch[i] << 7) + q * 4);
        a0 = di * v.x; a1 = di * v.y; a2 = di * v.z; a3 = di * v.w;
    }

    int e0 = rowptr[i], e1 = rowptr[i + 1];
    int deg = e1 - e0;
    int full = deg & ~7;
    int ee = e0 + full;
    for (int e = e0 + half * 4; e < ee; e += 8) {
        int2 r0 = ebuf2[e],     r1 = ebuf2[e + 1];
        int2 r2 = ebuf2[e + 2], r3 = ebuf2[e + 3];
        float4 w0 = *(const float4*)(zz + ((size_t)r0.x << 7) + q * 4);
        float4 w1 = *(const float4*)(zz + ((size_t)r1.x << 7) + q * 4);
        float4 w2 = *(const float4*)(zz + ((size_t)r2.x << 7) + q * 4);
        float4 w3 = *(const float4*)(zz + ((size_t)r3.x << 7) + q * 4);
        float n0 = __int_as_float(r0.y), n1 = __int_as_float(r1.y);
        float n2 = __int_as_float(r2.y), n3 = __int_as_float(r3.y);
        a0 += n0 * w0.x + n1 * w1.x + n2 * w2.x + n3 * w3.x;
        a1 += n0 * w0.y + n1 * w1.y + n2 * w2.y + n3 * w3.y;
        a2 += n0 * w0.z + n1 * w1.z + n2 * w2.z + n3 * w3.z;
        a3 += n0 * w0.w + n1 * w1.w + n2 * w2.w + n3 * w3.w;
    }
    for (int e = ee + half; e < e1; e += 2) {
        int2 r = ebuf2[e];
        float nm = __int_as_float(r.y);
        float4 w = *(const float4*)(zz + ((size_t)r.x << 7) + q * 4);
        a0 += nm * w.x; a1 += nm * w.y; a2 += nm * w.z; a3 += nm * w.w;
    }
    a0 += __shfl_xor(a0, 32);
    a1 += __shfl_xor(a1, 32);
    a2 += __shfl_xor(a2, 32);
    a3 += __shfl_xor(a3, 32);

    if (half == 0) {
        float4 b = *(const float4*)(bias + q * 4);
        float4 o;
        o.x = di * a0 + b.x;
        o.y = di * a1 + b.y;
        o.z = di * a2 + b.z;
        o.w = di * a3 + b.w;
        *(float4*)(out + (size_t)i * 128 + q * 4) = o;
    }
}

// ---------- fused fc + decoder + W3 transform ----------
__global__ __launch_bounds__(128) void fcdec_k(const float* __restrict__ pooled,
                                               const float* __restrict__ fcW,   // [128][64]
                                               const float* __restrict__ fcb,
                                               const float* __restrict__ decW,  // [64][128]
                                               const float* __restrict__ decb,
                                               const float* __restrict__ W3,    // [128][128]
                                               float* __restrict__ lat_out,
                                               float* __restrict__ zz)
{
    __shared__ float lat[64];
    __shared__ float zs[128];
    int g = blockIdx.x, c = threadIdx.x;
    if (c < 64) {
        const float* p = pooled + (size_t)g * 128;
        float a = fcb[c];
        #pragma unroll 8
        for (int k = 0; k < 128; k++) a = fmaf(p[k], fcW[(size_t)k * 64 + c], a);
        a = fmaxf(a, 0.f);
        lat[c] = a;
        lat_out[(size_t)g * 64 + c] = a;
    }
    __syncthreads();
    {
        float a = decb[c];
        #pragma unroll 8
        for (int k = 0; k < 64; k++) a = fmaf(lat[k], decW[(size_t)k * 128 + c], a);
        zs[c] = fmaxf(a, 0.f);
    }
    __syncthreads();
    float o = 0.f;
    #pragma unroll 8
    for (int k = 0; k < 128; k++) o = fmaf(zs[k], W3[(size_t)k * 128 + c], o);
    zz[(size_t)g * 128 + c] = o;
}

extern "C" void kernel_launch(void* const* d_in, const int* in_sizes, int n_in,
                              void* d_out, int out_size, void* d_ws, size_t ws_size,
                              hipStream_t stream)
{
    const float* x     = (const float*)d_in[0];
    const int*   ei    = (const int*)d_in[1];
    const int*   batch = (const int*)d_in[2];
    const float* W1  = (const float*)d_in[3];
    const float* b1  = (const float*)d_in[4];
    const float* W2  = (const float*)d_in[5];
    const float* b2  = (const float*)d_in[6];
    const float* fcW = (const float*)d_in[7];
    const float* fcb = (const float*)d_in[8];
    const float* decW= (const float*)d_in[9];
    const float* decb= (const float*)d_in[10];
    const float* W3  = (const float*)d_in[11];
    const float* b3  = (const float*)d_in[12];

    char* ws = (char*)d_ws;
    size_t off = 0;
    auto alloc = [&](size_t bytes) -> char* {
        char* p = ws + off;
        off = (off + bytes + 255) & ~(size_t)255;
        return p;
    };
    float* dinv     = (float*)alloc((size_t)NN * 4);
    int*   rowptr   = (int*)alloc((size_t)(NN + 1) * 4);
    int*   bcur     = (int*)alloc((size_t)NB * 4);
    int*   bbase    = (int*)alloc((size_t)NB * 4);
    int*   ebuf     = (int*)alloc((size_t)EE * 4);           // CSR src indices (4B/edge)
    int2*  ebuf2    = (int2*)alloc((size_t)EE * 8);          // {batch[src], dinv[src]}
    float* pooled   = (float*)alloc((size_t)GG * 128 * 4);
    float* zz       = (float*)alloc((size_t)GG * 128 * 4);
    f16x8* whi1     = (f16x8*)alloc(2048 * 16);              // W1 hi frags (32KB)
    f16x8* wlo1     = (f16x8*)alloc(2048 * 16);
    f16x8* whi2     = (f16x8*)alloc(2048 * 16);
    f16x8* wlo2     = (f16x8*)alloc(2048 * 16);
    __half* A       = (__half*)alloc((size_t)NN * 128 * 2);  // pre-scaled transformed feats (fp16)
    float* B        = (float*)alloc((size_t)NN * 128 * 4);   // h1 activations (f32)
    // eraw (NB*CAP*8 = 12.8MB) aliases B (25.6MB): consumed by binB before aggh1 writes B
    int2*  eraw     = (int2*)B;

    float* recon_out = (float*)d_out;
    float* lat_out   = (float*)d_out + (size_t)NN * 128;

    prep_k<<<19, 256, 0, stream>>>(W1, W2, whi1, wlo1, whi2, wlo2, bcur, pooled);
    binA_k<<<ABLK, 512, 0, stream>>>(ei, bcur, eraw);
    scanb2_k<<<1, 512, 0, stream>>>(bcur, bbase, rowptr);
    binB_k<<<NB, 512, 0, stream>>>(eraw, bcur, bbase, rowptr, dinv, ebuf);

    int gblk = (NN + 63) / 64;   // 782
    // conv1: A = dinv .* (x @ W1) (fp16) ; h1 = relu(dinv.*(agg(A)) + b1) -> B
    // aggh1 carries PBBB extra blocks that build ebuf2 (edge-parallel, no interaction)
    gemm_mfma3_k<<<gblk, 256, 0, stream>>>(x, whi1, wlo1, dinv, A, NN);
    aggh_k<<<NN + PBBB, 64, 0, stream>>>(A, rowptr, ebuf, dinv, b1, B, batch, ebuf2);
    // conv2: h2 rows pooled directly (h2 only feeds global_add_pool)
    gemm_mfma3_k<<<gblk, 256, 0, stream>>>(B, whi2, wlo2, dinv, A, NN);
    aggh_pool_k<<<NN, 64, 0, stream>>>(A, rowptr, ebuf, dinv, b2, batch, pooled);
    // fused fc/dec (latent out) + conv3
    fcdec_k<<<GG, 128, 0, stream>>>(pooled, fcW, fcb, decW, decb, W3, lat_out, zz);
    agg_out_k<<<NN, 64, 0, stream>>>(zz, batch, rowptr, ebuf2, dinv,
                                     b3, recon_out);
}

// Round 12
// 273.649 us; speedup vs baseline: 1.3210x; 1.3210x over previous
//
#include <hip/hip_runtime.h>
#include <hip/hip_fp16.h>

// Problem constants
static constexpr int NN   = 50000;
static constexpr int EE   = 800000;
static constexpr int GG   = 256;
static constexpr int PCH  = 16;                 // pooling chunks per graph
static constexpr int BK   = 128;                // targets per bucket
static constexpr int NB   = (NN + BK - 1) / BK; // 391 buckets (bucket = dst>>7)
static constexpr int CAP  = 4096;               // bucket region capacity (mean 2048, sigma 45)
static constexpr int CH   = 2048;               // edges per binA block
static constexpr int ABLK = (EE + CH - 1) / CH; // 391
static constexpr int PBBB = EE / 64;            // 12500 ebuf2-build blocks piggybacked on aggh1

typedef _Float16 f16;
typedef f16  f16x8 __attribute__((ext_vector_type(8)));
typedef float f32x4 __attribute__((ext_vector_type(4)));

// ---------- helpers ----------
__device__ __forceinline__ int lowerb(const int* __restrict__ b, int n, int v) {
    int lo = 0, hi = n;
    while (lo < hi) { int m = (lo + hi) >> 1; if (b[m] < v) lo = m + 1; else hi = m; }
    return lo;
}

// ---------- fused prep: W1/W2 frag conversion + bcur init + pooled zeroing ----------
// frag (nt,ks,kq,m) = W^T[nt*16+m][ks*32+kq*8 .. +8)  at index ((nt*4+ks)*4+kq)*16+m
__global__ __launch_bounds__(256) void prep_k(const float* __restrict__ W1,
                                              const float* __restrict__ W2,
                                              f16x8* __restrict__ whi1, f16x8* __restrict__ wlo1,
                                              f16x8* __restrict__ whi2, f16x8* __restrict__ wlo2,
                                              int* __restrict__ bcur,
                                              float* __restrict__ pooled)
{
    int blk = blockIdx.x, t = threadIdx.x;
    if (blk < 16) {
        const float* W = (blk < 8) ? W1 : W2;
        f16x8* wh = (blk < 8) ? whi1 : whi2;
        f16x8* wl = (blk < 8) ? wlo1 : wlo2;
        int tid = (blk & 7) * 256 + t;      // 0..2047
        int m  = tid & 15;
        int kq = (tid >> 4) & 3;
        int ks = (tid >> 6) & 3;
        int nt = tid >> 8;
        int n  = nt * 16 + m;
        int k0 = ks * 32 + kq * 8;
        f16x8 h8, l8;
        #pragma unroll
        for (int u = 0; u < 8; u++) {
            float x = W[(size_t)(k0 + u) * 128 + n];
            f16 h = (f16)x;
            h8[u] = h;
            l8[u] = (f16)(x - (float)h);
        }
        wh[tid] = h8;
        wl[tid] = l8;
    } else if (blk == 16) {
        for (int b = t; b < NB; b += 256) bcur[b] = b * CAP;
    } else {
        float4* p = (float4*)pooled;        // GG*128 floats = 8192 float4
        for (int j = (blk - 17) * 256 + t; j < GG * 32; j += 512)
            p[j] = make_float4(0.f, 0.f, 0.f, 0.f);
    }
}

// Pass A: partition edges into fixed-capacity bucket regions, coalesced flush.
__global__ __launch_bounds__(512) void binA_k(const int* __restrict__ ei,
                                              int* __restrict__ bcur,
                                              int2* __restrict__ eraw)
{
    __shared__ int2  stage[CH];
    __shared__ short sbid[CH];
    __shared__ int   hist[NB], loff[NB], gbase[NB], lcur[NB];
    __shared__ int   sc[512];

    int tid = threadIdx.x;
    int e0 = blockIdx.x * CH;
    int n = EE - e0; if (n > CH) n = CH;

    for (int b = tid; b < NB; b += 512) hist[b] = 0;
    __syncthreads();

    int2 r[CH / 512];
    #pragma unroll
    for (int k = 0; k < CH / 512; k++) {
        int s = k * 512 + tid;
        if (s < n) {
            int src = ei[e0 + s];
            int dst = ei[EE + e0 + s];
            r[k] = make_int2(src, dst);
            atomicAdd(&hist[dst >> 7], 1);
        }
    }
    __syncthreads();
    int v = (tid < NB) ? hist[tid] : 0;
    sc[tid] = v;
    __syncthreads();
    #pragma unroll
    for (int off = 1; off < 512; off <<= 1) {
        int add = (tid >= off) ? sc[tid - off] : 0;
        __syncthreads();
        sc[tid] += add;
        __syncthreads();
    }
    if (tid < NB) { int ex = sc[tid] - v; loff[tid] = ex; lcur[tid] = ex; }
    __syncthreads();
    for (int b = tid; b < NB; b += 512)
        gbase[b] = atomicAdd(&bcur[b], hist[b]);
    __syncthreads();
    #pragma unroll
    for (int k = 0; k < CH / 512; k++) {
        int s = k * 512 + tid;
        if (s < n) {
            int b = r[k].y >> 7;
            int slot = atomicAdd(&lcur[b], 1);
            stage[slot] = r[k];
            sbid[slot]  = (short)b;
        }
    }
    __syncthreads();
    for (int s = tid; s < n; s += 512) {
        int b = sbid[s];
        eraw[(size_t)gbase[b] + (s - loff[b])] = stage[s];
    }
}

// scan bucket totals -> bucket base offsets; rowptr[NN]=EE
__global__ __launch_bounds__(512) void scanb2_k(const int* __restrict__ bcur,
                                                int* __restrict__ bbase,
                                                int* __restrict__ rowptr)
{
    __shared__ int s[512];
    int t = threadIdx.x;
    int v = (t < NB) ? (bcur[t] - t * CAP) : 0;
    s[t] = v;
    __syncthreads();
    #pragma unroll
    for (int off = 1; off < 512; off <<= 1) {
        int add = (t >= off) ? s[t - off] : 0;
        __syncthreads();
        s[t] += add;
        __syncthreads();
    }
    if (t < NB) bbase[t] = s[t] - v;
    if (t == 0) rowptr[NN] = EE;
}

// Pass B: per bucket: LDS hist -> rowptr + dinv, place src ints at exact CSR slots
__global__ __launch_bounds__(512) void binB_k(const int2* __restrict__ eraw,
                                              const int* __restrict__ bcur,
                                              const int* __restrict__ bbase,
                                              int* __restrict__ rowptr,
                                              float* __restrict__ dinv,
                                              int* __restrict__ ebuf)
{
    __shared__ int hist[BK], excl[BK], cur[BK];
    int b = blockIdx.x, tid = threadIdx.x;
    int t0 = b << 7;
    int lim = NN - t0; if (lim > BK) lim = BK;
    int tot  = bcur[b] - b * CAP;
    int base = bbase[b];
    const int2* er = eraw + (size_t)b * CAP;

    if (tid < BK) hist[tid] = 0;
    __syncthreads();
    for (int s = tid; s < tot; s += 512) atomicAdd(&hist[er[s].y & 127], 1);
    __syncthreads();
    if (tid < BK) excl[tid] = hist[tid];
    __syncthreads();
    #pragma unroll
    for (int off = 1; off < BK; off <<= 1) {
        int add = (tid >= off && tid < BK) ? excl[tid - off] : 0;
        __syncthreads();
        if (tid < BK) excl[tid] += add;
        __syncthreads();
    }
    if (tid < BK) {
        int ex = excl[tid] - hist[tid];
        cur[tid] = base + ex;
        if (tid < lim) {
            rowptr[t0 + tid] = base + ex;
            dinv[t0 + tid]   = rsqrtf((float)(hist[tid] + 1));   // deg + self-loop
        }
    }
    __syncthreads();
    for (int s = tid; s < tot; s += 512) {
        int2 rec = er[s];
        int p = atomicAdd(&cur[rec.y & 127], 1);
        ebuf[p] = rec.x;
    }
}

// ---------- MFMA GEMM: out = dinv .* (in @ W), fp16 out, split-precision ----------
// 128 rows/block, 8 waves, 512 threads: half the LDS-staging instances of the 64-row
// version, full 32-wave/CU occupancy. hi table in 32KB LDS; lo read from L2.
// C/D: col=lane&15, row=(lane>>4)*4+reg (HW-verified).
__global__ __launch_bounds__(512) void gemm_mfma3_k(const float* __restrict__ in,
                                                    const f16x8* __restrict__ whi_f,
                                                    const f16x8* __restrict__ wlo_f,
                                                    const float* __restrict__ dinv,
                                                    __half* __restrict__ out,
                                                    int rows)
{
    __shared__ __align__(16) f16x8 sh[2048];    // 32KB: hi frags, same indexing as table
    int tid  = threadIdx.x;
    #pragma unroll
    for (int u = 0; u < 4; u++) sh[u * 512 + tid] = whi_f[u * 512 + tid];
    __syncthreads();

    int lane = tid & 63;
    int wv   = tid >> 6;                   // 0..7
    int rB   = blockIdx.x * 128 + wv * 16;
    int m    = lane & 15;
    int kq   = lane >> 4;                  // 0..3
    int r    = rB + m;
    int rr   = (r < rows) ? r : (rows - 1);

    // A-frags: k = ks*32 + kq*8 + [0..8)
    f16x8 ahi[4], alo[4];
    const float* rp = in + (size_t)rr * 128 + kq * 8;
    #pragma unroll
    for (int ks = 0; ks < 4; ks++) {
        float4 p0 = *(const float4*)(rp + ks * 32);
        float4 p1 = *(const float4*)(rp + ks * 32 + 4);
        float xs[8] = {p0.x, p0.y, p0.z, p0.w, p1.x, p1.y, p1.z, p1.w};
        #pragma unroll
        for (int u = 0; u < 8; u++) {
            f16 h = (f16)xs[u];
            ahi[ks][u] = h;
            alo[ks][u] = (f16)(xs[u] - (float)h);
        }
    }

    f32x4 acc[8];
    #pragma unroll
    for (int n = 0; n < 8; n++) acc[n] = (f32x4){0.f, 0.f, 0.f, 0.f};

    #pragma unroll
    for (int nt = 0; nt < 8; nt++) {
        #pragma unroll
        for (int ks = 0; ks < 4; ks++) {
            int idx = ((nt * 4 + ks) * 4 + kq) * 16 + m;
            f16x8 bh = sh[idx];
            f16x8 bl = wlo_f[idx];
            acc[nt] = __builtin_amdgcn_mfma_f32_16x16x32_f16(ahi[ks], bh, acc[nt], 0, 0, 0);
            acc[nt] = __builtin_amdgcn_mfma_f32_16x16x32_f16(alo[ks], bh, acc[nt], 0, 0, 0);
            acc[nt] = __builtin_amdgcn_mfma_f32_16x16x32_f16(ahi[ks], bl, acc[nt], 0, 0, 0);
        }
    }

    // epilogue: row = kq*4 + reg, col = nt*16 + m; scale by dinv[row], store f16
    int   orow[4];
    float dv[4];
    #pragma unroll
    for (int j = 0; j < 4; j++) {
        int gr = rB + kq * 4 + j;
        orow[j] = gr;
        dv[j]   = (gr < rows) ? dinv[gr] : 0.f;
    }
    #pragma unroll
    for (int nt = 0; nt < 8; nt++) {
        int c = nt * 16 + m;
        #pragma unroll
        for (int j = 0; j < 4; j++) {
            if (orow[j] < rows)
                out[(size_t)orow[j] * 128 + c] = __float2half(acc[nt][j] * dv[j]);
        }
    }
}

// ---------- aggregation gather body (PROVEN r8 version) ----------
__device__ __forceinline__ float4 gat4h(const __half* __restrict__ t, int s, int q)
{
    uint2 v = *(const uint2*)(t + ((size_t)s << 7) + q * 4);
    __half2 a = __builtin_bit_cast(__half2, v.x);
    __half2 b = __builtin_bit_cast(__half2, v.y);
    float2 fa = __half22float2(a), fb = __half22float2(b);
    return make_float4(fa.x, fa.y, fb.x, fb.y);
}

// core: accumulate sum_e t[src_e][q*4..q*4+4) + t[i][...] into a0..a3 (halves folded)
#define AGG_BODY                                                                 \
    int e0 = __builtin_amdgcn_readfirstlane(rowptr[i]);                          \
    int e1 = __builtin_amdgcn_readfirstlane(rowptr[i + 1]);                      \
    int deg = e1 - e0;                                                           \
    int idxsafe = (deg > 0) ? (e0 + min(lane, deg - 1)) : 0;                     \
    int myidx = ebuf[idxsafe];                                                   \
    float a0 = 0.f, a1 = 0.f, a2 = 0.f, a3 = 0.f;                                \
    if (half == 0) {                                                             \
        float4 v = gat4h(t, i, q);                                               \
        a0 = v.x; a1 = v.y; a2 = v.z; a3 = v.w;                                  \
    }                                                                            \
    int v   = min(deg, 64);                                                      \
    int c16 = v & ~15;                                                           \
    for (int j = half * 8; j < c16; j += 16) {                                   \
        int s0 = __shfl(myidx, j + 0), s1 = __shfl(myidx, j + 1);                \
        int s2 = __shfl(myidx, j + 2), s3 = __shfl(myidx, j + 3);                \
        int s4 = __shfl(myidx, j + 4), s5 = __shfl(myidx, j + 5);                \
        int s6 = __shfl(myidx, j + 6), s7 = __shfl(myidx, j + 7);                \
        float4 w0 = gat4h(t, s0, q);                                             \
        float4 w1 = gat4h(t, s1, q);                                             \
        float4 w2 = gat4h(t, s2, q);                                             \
        float4 w3 = gat4h(t, s3, q);                                             \
        float4 w4 = gat4h(t, s4, q);                                             \
        float4 w5 = gat4h(t, s5, q);                                             \
        float4 w6 = gat4h(t, s6, q);                                             \
        float4 w7 = gat4h(t, s7, q);                                             \
        a0 += w0.x + w1.x + w2.x + w3.x + w4.x + w5.x + w6.x + w7.x;             \
        a1 += w0.y + w1.y + w2.y + w3.y + w4.y + w5.y + w6.y + w7.y;             \
        a2 += w0.z + w1.z + w2.z + w3.z + w4.z + w5.z + w6.z + w7.z;             \
        a3 += w0.w + w1.w + w2.w + w3.w + w4.w + w5.w + w6.w + w7.w;             \
    }                                                                            \
    if (v - c16 >= 8) {                                                          \
        int j = c16 + half * 4;                                                  \
        int s0 = __shfl(myidx, j + 0), s1 = __shfl(myidx, j + 1);                \
        int s2 = __shfl(myidx, j + 2), s3 = __shfl(myidx, j + 3);                \
        float4 w0 = gat4h(t, s0, q);                                             \
        float4 w1 = gat4h(t, s1, q);                                             \
        float4 w2 = gat4h(t, s2, q);                                             \
        float4 w3 = gat4h(t, s3, q);                                             \
        a0 += w0.x + w1.x + w2.x + w3.x;                                         \
        a1 += w0.y + w1.y + w2.y + w3.y;                                         \
        a2 += w0.z + w1.z + w2.z + w3.z;                                         \
        a3 += w0.w + w1.w + w2.w + w3.w;                                         \
    }                                                                            \
    int done = c16 + ((v - c16) & 8);                                            \
    for (int j = done + half; j < v; j += 2) {                                   \
        int s = __shfl(myidx, j);                                                \
        float4 w = gat4h(t, s, q);                                               \
        a0 += w.x; a1 += w.y; a2 += w.z; a3 += w.w;                              \
    }                                                                            \
    for (int e = e0 + 64 + half; e < e1; e += 2) {                               \
        float4 w = gat4h(t, ebuf[e], q);                                         \
        a0 += w.x; a1 += w.y; a2 += w.z; a3 += w.w;                              \
    }                                                                            \
    a0 += __shfl_xor(a0, 32);                                                    \
    a1 += __shfl_xor(a1, 32);                                                    \
    a2 += __shfl_xor(a2, 32);                                                    \
    a3 += __shfl_xor(a3, 32);

// conv aggregation -> writes relu'd rows; blocks >= NN piggyback the ebuf2 build
__global__ __launch_bounds__(64) void aggh_k(const __half* __restrict__ t,
                                             const int* __restrict__ rowptr,
                                             const int* __restrict__ ebuf,
                                             const float* __restrict__ dinv,
                                             const float* __restrict__ bias,
                                             float* __restrict__ out,
                                             const int* __restrict__ batch,
                                             int2* __restrict__ ebuf2)
{
    int bid  = blockIdx.x;
    int lane = threadIdx.x;
    if (bid >= NN) {                      // piggybacked ebuf2 build: 64 edges/block
        int e = (bid - NN) * 64 + lane;
        if (e < EE) {
            int src = ebuf[e];
            ebuf2[e] = make_int2(batch[src], __float_as_int(dinv[src]));
        }
        return;
    }
    int i    = bid;
    int half = lane >> 5;
    int q    = lane & 31;
    AGG_BODY
    if (half == 0) {
        float di = dinv[i];
        float4 b = *(const float4*)(bias + q * 4);
        float4 o;
        o.x = fmaxf(di * a0 + b.x, 0.f);
        o.y = fmaxf(di * a1 + b.y, 0.f);
        o.z = fmaxf(di * a2 + b.z, 0.f);
        o.w = fmaxf(di * a3 + b.w, 0.f);
        *(float4*)(out + (size_t)i * 128 + q * 4) = o;
    }
}

// conv3 aggregation, paired-edge (PROVEN r8 version): ebuf2 = {bg, w=dinv[src]};
// zz (131KB) L2-resident. Lane covers float4; halves process alternate edge-chunks.
__global__ __launch_bounds__(64) void agg_out_k(const float* __restrict__ zz,
                                                const int* __restrict__ batch,
                                                const int* __restrict__ rowptr,
                                                const int2* __restrict__ ebuf2,
                                                const float* __restrict__ dinv,
                                                const float* __restrict__ bias,
                                                float* __restrict__ out)
{
    int i    = blockIdx.x;
    int lane = threadIdx.x;
    int half = lane >> 5;
    int q    = lane & 31;
    float di = dinv[i];

    float a0 = 0.f, a1 = 0.f, a2 = 0.f, a3 = 0.f;
    if (half == 0) {                     // self term: di * zz[batch[i]]
        float4 v = *(const float4*)(zz + ((size_t)batch[i] << 7) + q * 4);
        a0 = di * v.x; a1 = di * v.y; a2 = di * v.z; a3 = di * v.w;
    }

    int e0 = rowptr[i], e1 = rowptr[i + 1];
    int deg = e1 - e0;
    int full = deg & ~7;
    int ee = e0 + full;
    for (int e = e0 + half * 4; e < ee; e += 8) {
        int2 r0 = ebuf2[e],     r1 = ebuf2[e + 1];
        int2 r2 = ebuf2[e + 2], r3 = ebuf2[e + 3];
        float4 w0 = *(const float4*)(zz + ((size_t)r0.x << 7) + q * 4);
        float4 w1 = *(const float4*)(zz + ((size_t)r1.x << 7) + q * 4);
        float4 w2 = *(const float4*)(zz + ((size_t)r2.x << 7) + q * 4);
        float4 w3 = *(const float4*)(zz + ((size_t)r3.x << 7) + q * 4);
        float n0 = __int_as_float(r0.y), n1 = __int_as_float(r1.y);
        float n2 = __int_as_float(r2.y), n3 = __int_as_float(r3.y);
        a0 += n0 * w0.x + n1 * w1.x + n2 * w2.x + n3 * w3.x;
        a1 += n0 * w0.y + n1 * w1.y + n2 * w2.y + n3 * w3.y;
        a2 += n0 * w0.z + n1 * w1.z + n2 * w2.z + n3 * w3.z;
        a3 += n0 * w0.w + n1 * w1.w + n2 * w2.w + n3 * w3.w;
    }
    for (int e = ee + half; e < e1; e += 2) {
        int2 r = ebuf2[e];
        float nm = __int_as_float(r.y);
        float4 w = *(const float4*)(zz + ((size_t)r.x << 7) + q * 4);
        a0 += nm * w.x; a1 += nm * w.y; a2 += nm * w.z; a3 += nm * w.w;
    }
    a0 += __shfl_xor(a0, 32);
    a1 += __shfl_xor(a1, 32);
    a2 += __shfl_xor(a2, 32);
    a3 += __shfl_xor(a3, 32);

    if (half == 0) {
        float4 b = *(const float4*)(bias + q * 4);
        float4 o;
        o.x = di * a0 + b.x;
        o.y = di * a1 + b.y;
        o.z = di * a2 + b.z;
        o.w = di * a3 + b.w;
        *(float4*)(out + (size_t)i * 128 + q * 4) = o;
    }
}

// ---------- pooling (hierarchical: chunk partial sums, then one atomic per chunk) ----------
__global__ __launch_bounds__(128) void pool2_k(const float* __restrict__ h2,
                                               const int* __restrict__ batch,
                                               float* __restrict__ pooled)
{
    int g = blockIdx.x;
    int c = blockIdx.y;
    int f = threadIdx.x;
    int bs = lowerb(batch, NN, g);
    int be = lowerb(batch, NN, g + 1);
    int len = be - bs;
    int cs = bs + (int)(((long long)len * c) / PCH);
    int ce = bs + (int)(((long long)len * (c + 1)) / PCH);
    float a = 0.f;
    for (int i = cs; i < ce; i++) a += h2[(size_t)i * 128 + f];
    if (ce > cs) atomicAdd(&pooled[(size_t)g * 128 + f], a);
}

// ---------- fused fc + decoder + W3 transform ----------
__global__ __launch_bounds__(128) void fcdec_k(const float* __restrict__ pooled,
                                               const float* __restrict__ fcW,   // [128][64]
                                               const float* __restrict__ fcb,
                                               const float* __restrict__ decW,  // [64][128]
                                               const float* __restrict__ decb,
                                               const float* __restrict__ W3,    // [128][128]
                                               float* __restrict__ lat_out,
                                               float* __restrict__ zz)
{
    __shared__ float lat[64];
    __shared__ float zs[128];
    int g = blockIdx.x, c = threadIdx.x;
    if (c < 64) {
        const float* p = pooled + (size_t)g * 128;
        float a = fcb[c];
        #pragma unroll 8
        for (int k = 0; k < 128; k++) a = fmaf(p[k], fcW[(size_t)k * 64 + c], a);
        a = fmaxf(a, 0.f);
        lat[c] = a;
        lat_out[(size_t)g * 64 + c] = a;
    }
    __syncthreads();
    {
        float a = decb[c];
        #pragma unroll 8
        for (int k = 0; k < 64; k++) a = fmaf(lat[k], decW[(size_t)k * 128 + c], a);
        zs[c] = fmaxf(a, 0.f);
    }
    __syncthreads();
    float o = 0.f;
    #pragma unroll 8
    for (int k = 0; k < 128; k++) o = fmaf(zs[k], W3[(size_t)k * 128 + c], o);
    zz[(size_t)g * 128 + c] = o;
}

extern "C" void kernel_launch(void* const* d_in, const int* in_sizes, int n_in,
                              void* d_out, int out_size, void* d_ws, size_t ws_size,
                              hipStream_t stream)
{
    const float* x     = (const float*)d_in[0];
    const int*   ei    = (const int*)d_in[1];
    const int*   batch = (const int*)d_in[2];
    const float* W1  = (const float*)d_in[3];
    const float* b1  = (const float*)d_in[4];
    const float* W2  = (const float*)d_in[5];
    const float* b2  = (const float*)d_in[6];
    const float* fcW = (const float*)d_in[7];
    const float* fcb = (const float*)d_in[8];
    const float* decW= (const float*)d_in[9];
    const float* decb= (const float*)d_in[10];
    const float* W3  = (const float*)d_in[11];
    const float* b3  = (const float*)d_in[12];

    char* ws = (char*)d_ws;
    size_t off = 0;
    auto alloc = [&](size_t bytes) -> char* {
        char* p = ws + off;
        off = (off + bytes + 255) & ~(size_t)255;
        return p;
    };
    float* dinv     = (float*)alloc((size_t)NN * 4);
    int*   rowptr   = (int*)alloc((size_t)(NN + 1) * 4);
    int*   bcur     = (int*)alloc((size_t)NB * 4);
    int*   bbase    = (int*)alloc((size_t)NB * 4);
    int*   ebuf     = (int*)alloc((size_t)EE * 4);           // CSR src indices (4B/edge)
    int2*  ebuf2    = (int2*)alloc((size_t)EE * 8);          // {batch[src], dinv[src]}
    float* pooled   = (float*)alloc((size_t)GG * 128 * 4);
    float* zz       = (float*)alloc((size_t)GG * 128 * 4);
    f16x8* whi1     = (f16x8*)alloc(2048 * 16);              // W1 hi frags (32KB)
    f16x8* wlo1     = (f16x8*)alloc(2048 * 16);
    f16x8* whi2     = (f16x8*)alloc(2048 * 16);
    f16x8* wlo2     = (f16x8*)alloc(2048 * 16);
    __half* A       = (__half*)alloc((size_t)NN * 128 * 2);  // pre-scaled transformed feats (fp16)
    float* B        = (float*)alloc((size_t)NN * 128 * 4);   // h1/h2 activations (f32)
    // eraw (NB*CAP*8 = 12.8MB) aliases B (25.6MB): consumed by binB before aggh1 writes B
    int2*  eraw     = (int2*)B;

    float* recon_out = (float*)d_out;
    float* lat_out   = (float*)d_out + (size_t)NN * 128;

    prep_k<<<19, 256, 0, stream>>>(W1, W2, whi1, wlo1, whi2, wlo2, bcur, pooled);
    binA_k<<<ABLK, 512, 0, stream>>>(ei, bcur, eraw);
    scanb2_k<<<1, 512, 0, stream>>>(bcur, bbase, rowptr);
    binB_k<<<NB, 512, 0, stream>>>(eraw, bcur, bbase, rowptr, dinv, ebuf);

    int gblk = (NN + 127) / 128;   // 391
    // conv1: A = dinv .* (x @ W1) (fp16) ; h1 = relu(dinv.*(agg(A)) + b1) -> B
    // aggh1 carries PBBB extra blocks that build ebuf2 (edge-parallel, no interaction)
    gemm_mfma3_k<<<gblk, 512, 0, stream>>>(x, whi1, wlo1, dinv, A, NN);
    aggh_k<<<NN + PBBB, 64, 0, stream>>>(A, rowptr, ebuf, dinv, b1, B, batch, ebuf2);
    // conv2: h2 -> B (piggyback branch inert at grid=NN)
    gemm_mfma3_k<<<gblk, 512, 0, stream>>>(B, whi2, wlo2, dinv, A, NN);
    aggh_k<<<NN, 64, 0, stream>>>(A, rowptr, ebuf, dinv, b2, B, batch, ebuf2);
    // pool + fused fc/dec (latent out) + conv3
    pool2_k<<<dim3(GG, PCH), 128, 0, stream>>>(B, batch, pooled);
    fcdec_k<<<GG, 128, 0, stream>>>(pooled, fcW, fcb, decW, decb, W3, lat_out, zz);
    agg_out_k<<<NN, 64, 0, stream>>>(zz, batch, rowptr, ebuf2, dinv,
                                     b3, recon_out);
}

// Round 13
// 271.799 us; speedup vs baseline: 1.3300x; 1.0068x over previous
//
#include <hip/hip_runtime.h>
#include <hip/hip_fp16.h>

// Problem constants
static constexpr int NN   = 50000;
static constexpr int EE   = 800000;
static constexpr int GG   = 256;
static constexpr int PCH  = 16;                 // pooling chunks per graph
static constexpr int BK   = 128;                // targets per bucket
static constexpr int NB   = (NN + BK - 1) / BK; // 391 buckets (bucket = dst>>7)
static constexpr int CAP  = 4096;               // bucket region capacity (mean 2048, sigma 45)
static constexpr int CH   = 2048;               // edges per binA block
static constexpr int ABLK = (EE + CH - 1) / CH; // 391
static constexpr int PBBB = EE / 64;            // 12500 ebuf2-build blocks piggybacked on aggh1

typedef _Float16 f16;
typedef f16  f16x8 __attribute__((ext_vector_type(8)));
typedef float f32x4 __attribute__((ext_vector_type(4)));

// ---------- helpers ----------
__device__ __forceinline__ int lowerb(const int* __restrict__ b, int n, int v) {
    int lo = 0, hi = n;
    while (lo < hi) { int m = (lo + hi) >> 1; if (b[m] < v) lo = m + 1; else hi = m; }
    return lo;
}

// ---------- fused prep: W1/W2 frag conversion + bcur init + pooled zeroing ----------
// frag (nt,ks,kq,m) = W^T[nt*16+m][ks*32+kq*8 .. +8)  at index ((nt*4+ks)*4+kq)*16+m
__global__ __launch_bounds__(256) void prep_k(const float* __restrict__ W1,
                                              const float* __restrict__ W2,
                                              f16x8* __restrict__ whi1, f16x8* __restrict__ wlo1,
                                              f16x8* __restrict__ whi2, f16x8* __restrict__ wlo2,
                                              int* __restrict__ bcur,
                                              float* __restrict__ pooled)
{
    int blk = blockIdx.x, t = threadIdx.x;
    if (blk < 16) {
        const float* W = (blk < 8) ? W1 : W2;
        f16x8* wh = (blk < 8) ? whi1 : whi2;
        f16x8* wl = (blk < 8) ? wlo1 : wlo2;
        int tid = (blk & 7) * 256 + t;      // 0..2047
        int m  = tid & 15;
        int kq = (tid >> 4) & 3;
        int ks = (tid >> 6) & 3;
        int nt = tid >> 8;
        int n  = nt * 16 + m;
        int k0 = ks * 32 + kq * 8;
        f16x8 h8, l8;
        #pragma unroll
        for (int u = 0; u < 8; u++) {
            float x = W[(size_t)(k0 + u) * 128 + n];
            f16 h = (f16)x;
            h8[u] = h;
            l8[u] = (f16)(x - (float)h);
        }
        wh[tid] = h8;
        wl[tid] = l8;
    } else if (blk == 16) {
        for (int b = t; b < NB; b += 256) bcur[b] = b * CAP;
    } else {
        float4* p = (float4*)pooled;        // GG*128 floats = 8192 float4
        for (int j = (blk - 17) * 256 + t; j < GG * 32; j += 512)
            p[j] = make_float4(0.f, 0.f, 0.f, 0.f);
    }
}

// Pass A: partition edges into fixed-capacity bucket regions, coalesced flush.
__global__ __launch_bounds__(512) void binA_k(const int* __restrict__ ei,
                                              int* __restrict__ bcur,
                                              int2* __restrict__ eraw)
{
    __shared__ int2  stage[CH];
    __shared__ short sbid[CH];
    __shared__ int   hist[NB], loff[NB], gbase[NB], lcur[NB];
    __shared__ int   sc[512];

    int tid = threadIdx.x;
    int e0 = blockIdx.x * CH;
    int n = EE - e0; if (n > CH) n = CH;

    for (int b = tid; b < NB; b += 512) hist[b] = 0;
    __syncthreads();

    int2 r[CH / 512];
    #pragma unroll
    for (int k = 0; k < CH / 512; k++) {
        int s = k * 512 + tid;
        if (s < n) {
            int src = ei[e0 + s];
            int dst = ei[EE + e0 + s];
            r[k] = make_int2(src, dst);
            atomicAdd(&hist[dst >> 7], 1);
        }
    }
    __syncthreads();
    int v = (tid < NB) ? hist[tid] : 0;
    sc[tid] = v;
    __syncthreads();
    #pragma unroll
    for (int off = 1; off < 512; off <<= 1) {
        int add = (tid >= off) ? sc[tid - off] : 0;
        __syncthreads();
        sc[tid] += add;
        __syncthreads();
    }
    if (tid < NB) { int ex = sc[tid] - v; loff[tid] = ex; lcur[tid] = ex; }
    __syncthreads();
    for (int b = tid; b < NB; b += 512)
        gbase[b] = atomicAdd(&bcur[b], hist[b]);
    __syncthreads();
    #pragma unroll
    for (int k = 0; k < CH / 512; k++) {
        int s = k * 512 + tid;
        if (s < n) {
            int b = r[k].y >> 7;
            int slot = atomicAdd(&lcur[b], 1);
            stage[slot] = r[k];
            sbid[slot]  = (short)b;
        }
    }
    __syncthreads();
    for (int s = tid; s < n; s += 512) {
        int b = sbid[s];
        eraw[(size_t)gbase[b] + (s - loff[b])] = stage[s];
    }
}

// scan bucket totals -> bucket base offsets; rowptr[NN]=EE
__global__ __launch_bounds__(512) void scanb2_k(const int* __restrict__ bcur,
                                                int* __restrict__ bbase,
                                                int* __restrict__ rowptr)
{
    __shared__ int s[512];
    int t = threadIdx.x;
    int v = (t < NB) ? (bcur[t] - t * CAP) : 0;
    s[t] = v;
    __syncthreads();
    #pragma unroll
    for (int off = 1; off < 512; off <<= 1) {
        int add = (t >= off) ? s[t - off] : 0;
        __syncthreads();
        s[t] += add;
        __syncthreads();
    }
    if (t < NB) bbase[t] = s[t] - v;
    if (t == 0) rowptr[NN] = EE;
}

// Pass B: per bucket: LDS hist -> rowptr + dinv, place src ints at exact CSR slots
__global__ __launch_bounds__(512) void binB_k(const int2* __restrict__ eraw,
                                              const int* __restrict__ bcur,
                                              const int* __restrict__ bbase,
                                              int* __restrict__ rowptr,
                                              float* __restrict__ dinv,
                                              int* __restrict__ ebuf)
{
    __shared__ int hist[BK], excl[BK], cur[BK];
    int b = blockIdx.x, tid = threadIdx.x;
    int t0 = b << 7;
    int lim = NN - t0; if (lim > BK) lim = BK;
    int tot  = bcur[b] - b * CAP;
    int base = bbase[b];
    const int2* er = eraw + (size_t)b * CAP;

    if (tid < BK) hist[tid] = 0;
    __syncthreads();
    for (int s = tid; s < tot; s += 512) atomicAdd(&hist[er[s].y & 127], 1);
    __syncthreads();
    if (tid < BK) excl[tid] = hist[tid];
    __syncthreads();
    #pragma unroll
    for (int off = 1; off < BK; off <<= 1) {
        int add = (tid >= off && tid < BK) ? excl[tid - off] : 0;
        __syncthreads();
        if (tid < BK) excl[tid] += add;
        __syncthreads();
    }
    if (tid < BK) {
        int ex = excl[tid] - hist[tid];
        cur[tid] = base + ex;
        if (tid < lim) {
            rowptr[t0 + tid] = base + ex;
            dinv[t0 + tid]   = rsqrtf((float)(hist[tid] + 1));   // deg + self-loop
        }
    }
    __syncthreads();
    for (int s = tid; s < tot; s += 512) {
        int2 rec = er[s];
        int p = atomicAdd(&cur[rec.y & 127], 1);
        ebuf[p] = rec.x;
    }
}

// ---------- MFMA GEMM (f32 input): out = dinv .* (in @ W), fp16 out, split-precision ----
// 128 rows/block, 8 waves. hi table in 32KB LDS; lo from L2. 3 MFMAs/tile.
// C/D: col=lane&15, row=(lane>>4)*4+reg (HW-verified).
__global__ __launch_bounds__(512) void gemm_mfma3_k(const float* __restrict__ in,
                                                    const f16x8* __restrict__ whi_f,
                                                    const f16x8* __restrict__ wlo_f,
                                                    const float* __restrict__ dinv,
                                                    __half* __restrict__ out,
                                                    int rows)
{
    __shared__ __align__(16) f16x8 sh[2048];    // 32KB: hi frags, same indexing as table
    int tid  = threadIdx.x;
    #pragma unroll
    for (int u = 0; u < 4; u++) sh[u * 512 + tid] = whi_f[u * 512 + tid];
    __syncthreads();

    int lane = tid & 63;
    int wv   = tid >> 6;                   // 0..7
    int rB   = blockIdx.x * 128 + wv * 16;
    int m    = lane & 15;
    int kq   = lane >> 4;                  // 0..3
    int r    = rB + m;
    int rr   = (r < rows) ? r : (rows - 1);

    // A-frags: k = ks*32 + kq*8 + [0..8)
    f16x8 ahi[4], alo[4];
    const float* rp = in + (size_t)rr * 128 + kq * 8;
    #pragma unroll
    for (int ks = 0; ks < 4; ks++) {
        float4 p0 = *(const float4*)(rp + ks * 32);
        float4 p1 = *(const float4*)(rp + ks * 32 + 4);
        float xs[8] = {p0.x, p0.y, p0.z, p0.w, p1.x, p1.y, p1.z, p1.w};
        #pragma unroll
        for (int u = 0; u < 8; u++) {
            f16 h = (f16)xs[u];
            ahi[ks][u] = h;
            alo[ks][u] = (f16)(xs[u] - (float)h);
        }
    }

    f32x4 acc[8];
    #pragma unroll
    for (int n = 0; n < 8; n++) acc[n] = (f32x4){0.f, 0.f, 0.f, 0.f};

    #pragma unroll
    for (int nt = 0; nt < 8; nt++) {
        #pragma unroll
        for (int ks = 0; ks < 4; ks++) {
            int idx = ((nt * 4 + ks) * 4 + kq) * 16 + m;
            f16x8 bh = sh[idx];
            f16x8 bl = wlo_f[idx];
            acc[nt] = __builtin_amdgcn_mfma_f32_16x16x32_f16(ahi[ks], bh, acc[nt], 0, 0, 0);
            acc[nt] = __builtin_amdgcn_mfma_f32_16x16x32_f16(alo[ks], bh, acc[nt], 0, 0, 0);
            acc[nt] = __builtin_amdgcn_mfma_f32_16x16x32_f16(ahi[ks], bl, acc[nt], 0, 0, 0);
        }
    }

    // epilogue: row = kq*4 + reg, col = nt*16 + m; scale by dinv[row], store f16
    int   orow[4];
    float dv[4];
    #pragma unroll
    for (int j = 0; j < 4; j++) {
        int gr = rB + kq * 4 + j;
        orow[j] = gr;
        dv[j]   = (gr < rows) ? dinv[gr] : 0.f;
    }
    #pragma unroll
    for (int nt = 0; nt < 8; nt++) {
        int c = nt * 16 + m;
        #pragma unroll
        for (int j = 0; j < 4; j++) {
            if (orow[j] < rows)
                out[(size_t)orow[j] * 128 + c] = __float2half(acc[nt][j] * dv[j]);
        }
    }
}

// ---------- MFMA GEMM (fp16 input): A-frag exact in fp16 (lo(A)=0) -> only 2 MFMAs/tile ----
// in is fp16 row-major [rows][128]; frag = 8 contiguous halves (one 16B load per ks).
__global__ __launch_bounds__(512) void gemm_mfma2h_k(const __half* __restrict__ in,
                                                     const f16x8* __restrict__ whi_f,
                                                     const f16x8* __restrict__ wlo_f,
                                                     const float* __restrict__ dinv,
                                                     __half* __restrict__ out,
                                                     int rows)
{
    __shared__ __align__(16) f16x8 sh[2048];    // 32KB hi frags
    int tid  = threadIdx.x;
    #pragma unroll
    for (int u = 0; u < 4; u++) sh[u * 512 + tid] = whi_f[u * 512 + tid];
    __syncthreads();

    int lane = tid & 63;
    int wv   = tid >> 6;
    int rB   = blockIdx.x * 128 + wv * 16;
    int m    = lane & 15;
    int kq   = lane >> 4;
    int r    = rB + m;
    int rr   = (r < rows) ? r : (rows - 1);

    // A-frags: 8 contiguous fp16 at k = ks*32 + kq*8 (16B aligned)
    f16x8 ah[4];
    const f16* rp = (const f16*)in + (size_t)rr * 128 + kq * 8;
    #pragma unroll
    for (int ks = 0; ks < 4; ks++)
        ah[ks] = *(const f16x8*)(rp + ks * 32);

    f32x4 acc[8];
    #pragma unroll
    for (int n = 0; n < 8; n++) acc[n] = (f32x4){0.f, 0.f, 0.f, 0.f};

    #pragma unroll
    for (int nt = 0; nt < 8; nt++) {
        #pragma unroll
        for (int ks = 0; ks < 4; ks++) {
            int idx = ((nt * 4 + ks) * 4 + kq) * 16 + m;
            f16x8 bh = sh[idx];
            f16x8 bl = wlo_f[idx];
            acc[nt] = __builtin_amdgcn_mfma_f32_16x16x32_f16(ah[ks], bh, acc[nt], 0, 0, 0);
            acc[nt] = __builtin_amdgcn_mfma_f32_16x16x32_f16(ah[ks], bl, acc[nt], 0, 0, 0);
        }
    }

    int   orow[4];
    float dv[4];
    #pragma unroll
    for (int j = 0; j < 4; j++) {
        int gr = rB + kq * 4 + j;
        orow[j] = gr;
        dv[j]   = (gr < rows) ? dinv[gr] : 0.f;
    }
    #pragma unroll
    for (int nt = 0; nt < 8; nt++) {
        int c = nt * 16 + m;
        #pragma unroll
        for (int j = 0; j < 4; j++) {
            if (orow[j] < rows)
                out[(size_t)orow[j] * 128 + c] = __float2half(acc[nt][j] * dv[j]);
        }
    }
}

// ---------- aggregation gather body (PROVEN r8 version) ----------
__device__ __forceinline__ float4 gat4h(const __half* __restrict__ t, int s, int q)
{
    uint2 v = *(const uint2*)(t + ((size_t)s << 7) + q * 4);
    __half2 a = __builtin_bit_cast(__half2, v.x);
    __half2 b = __builtin_bit_cast(__half2, v.y);
    float2 fa = __half22float2(a), fb = __half22float2(b);
    return make_float4(fa.x, fa.y, fb.x, fb.y);
}

// core: accumulate sum_e t[src_e][q*4..q*4+4) + t[i][...] into a0..a3 (halves folded)
#define AGG_BODY                                                                 \
    int e0 = __builtin_amdgcn_readfirstlane(rowptr[i]);                          \
    int e1 = __builtin_amdgcn_readfirstlane(rowptr[i + 1]);                      \
    int deg = e1 - e0;                                                           \
    int idxsafe = (deg > 0) ? (e0 + min(lane, deg - 1)) : 0;                     \
    int myidx = ebuf[idxsafe];                                                   \
    float a0 = 0.f, a1 = 0.f, a2 = 0.f, a3 = 0.f;                                \
    if (half == 0) {                                                             \
        float4 v = gat4h(t, i, q);                                               \
        a0 = v.x; a1 = v.y; a2 = v.z; a3 = v.w;                                  \
    }                                                                            \
    int v   = min(deg, 64);                                                      \
    int c16 = v & ~15;                                                           \
    for (int j = half * 8; j < c16; j += 16) {                                   \
        int s0 = __shfl(myidx, j + 0), s1 = __shfl(myidx, j + 1);                \
        int s2 = __shfl(myidx, j + 2), s3 = __shfl(myidx, j + 3);                \
        int s4 = __shfl(myidx, j + 4), s5 = __shfl(myidx, j + 5);                \
        int s6 = __shfl(myidx, j + 6), s7 = __shfl(myidx, j + 7);                \
        float4 w0 = gat4h(t, s0, q);                                             \
        float4 w1 = gat4h(t, s1, q);                                             \
        float4 w2 = gat4h(t, s2, q);                                             \
        float4 w3 = gat4h(t, s3, q);                                             \
        float4 w4 = gat4h(t, s4, q);                                             \
        float4 w5 = gat4h(t, s5, q);                                             \
        float4 w6 = gat4h(t, s6, q);                                             \
        float4 w7 = gat4h(t, s7, q);                                             \
        a0 += w0.x + w1.x + w2.x + w3.x + w4.x + w5.x + w6.x + w7.x;             \
        a1 += w0.y + w1.y + w2.y + w3.y + w4.y + w5.y + w6.y + w7.y;             \
        a2 += w0.z + w1.z + w2.z + w3.z + w4.z + w5.z + w6.z + w7.z;             \
        a3 += w0.w + w1.w + w2.w + w3.w + w4.w + w5.w + w6.w + w7.w;             \
    }                                                                            \
    if (v - c16 >= 8) {                                                          \
        int j = c16 + half * 4;                                                  \
        int s0 = __shfl(myidx, j + 0), s1 = __shfl(myidx, j + 1);                \
        int s2 = __shfl(myidx, j + 2), s3 = __shfl(myidx, j + 3);                \
        float4 w0 = gat4h(t, s0, q);                                             \
        float4 w1 = gat4h(t, s1, q);                                             \
        float4 w2 = gat4h(t, s2, q);                                             \
        float4 w3 = gat4h(t, s3, q);                                             \
        a0 += w0.x + w1.x + w2.x + w3.x;                                         \
        a1 += w0.y + w1.y + w2.y + w3.y;                                         \
        a2 += w0.z + w1.z + w2.z + w3.z;                                         \
        a3 += w0.w + w1.w + w2.w + w3.w;                                         \
    }                                                                            \
    int done = c16 + ((v - c16) & 8);                                            \
    for (int j = done + half; j < v; j += 2) {                                   \
        int s = __shfl(myidx, j);                                                \
        float4 w = gat4h(t, s, q);                                               \
        a0 += w.x; a1 += w.y; a2 += w.z; a3 += w.w;                              \
    }                                                                            \
    for (int e = e0 + 64 + half; e < e1; e += 2) {                               \
        float4 w = gat4h(t, ebuf[e], q);                                         \
        a0 += w.x; a1 += w.y; a2 += w.z; a3 += w.w;                              \
    }                                                                            \
    a0 += __shfl_xor(a0, 32);                                                    \
    a1 += __shfl_xor(a1, 32);                                                    \
    a2 += __shfl_xor(a2, 32);                                                    \
    a3 += __shfl_xor(a3, 32);

// conv aggregation -> writes relu'd rows as fp16; blocks >= NN piggyback the ebuf2 build
__global__ __launch_bounds__(64) void aggh_k(const __half* __restrict__ t,
                                             const int* __restrict__ rowptr,
                                             const int* __restrict__ ebuf,
                                             const float* __restrict__ dinv,
                                             const float* __restrict__ bias,
                                             __half* __restrict__ out,
                                             const int* __restrict__ batch,
                                             int2* __restrict__ ebuf2)
{
    int bid  = blockIdx.x;
    int lane = threadIdx.x;
    if (bid >= NN) {                      // piggybacked ebuf2 build: 64 edges/block
        int e = (bid - NN) * 64 + lane;
        if (e < EE) {
            int src = ebuf[e];
            ebuf2[e] = make_int2(batch[src], __float_as_int(dinv[src]));
        }
        return;
    }
    int i    = bid;
    int half = lane >> 5;
    int q    = lane & 31;
    AGG_BODY
    if (half == 0) {
        float di = dinv[i];
        float4 b = *(const float4*)(bias + q * 4);
        float ox = fmaxf(di * a0 + b.x, 0.f);
        float oy = fmaxf(di * a1 + b.y, 0.f);
        float oz = fmaxf(di * a2 + b.z, 0.f);
        float ow = fmaxf(di * a3 + b.w, 0.f);
        __half2 h01 = __floats2half2_rn(ox, oy);
        __half2 h23 = __floats2half2_rn(oz, ow);
        uint2 u = make_uint2(__builtin_bit_cast(unsigned, h01),
                             __builtin_bit_cast(unsigned, h23));
        *(uint2*)(out + (size_t)i * 128 + q * 4) = u;
    }
}

// conv3 aggregation, paired-edge (PROVEN r8 version): ebuf2 = {bg, w=dinv[src]};
// zz (131KB) L2-resident. Lane covers float4; halves process alternate edge-chunks.
__global__ __launch_bounds__(64) void agg_out_k(const float* __restrict__ zz,
                                                const int* __restrict__ batch,
                                                const int* __restrict__ rowptr,
                                                const int2* __restrict__ ebuf2,
                                                const float* __restrict__ dinv,
                                                const float* __restrict__ bias,
                                                float* __restrict__ out)
{
    int i    = blockIdx.x;
    int lane = threadIdx.x;
    int half = lane >> 5;
    int q    = lane & 31;
    float di = dinv[i];

    float a0 = 0.f, a1 = 0.f, a2 = 0.f, a3 = 0.f;
    if (half == 0) {                     // self term: di * zz[batch[i]]
        float4 v = *(const float4*)(zz + ((size_t)batch[i] << 7) + q * 4);
        a0 = di * v.x; a1 = di * v.y; a2 = di * v.z; a3 = di * v.w;
    }

    int e0 = rowptr[i], e1 = rowptr[i + 1];
    int deg = e1 - e0;
    int full = deg & ~7;
    int ee = e0 + full;
    for (int e = e0 + half * 4; e < ee; e += 8) {
        int2 r0 = ebuf2[e],     r1 = ebuf2[e + 1];
        int2 r2 = ebuf2[e + 2], r3 = ebuf2[e + 3];
        float4 w0 = *(const float4*)(zz + ((size_t)r0.x << 7) + q * 4);
        float4 w1 = *(const float4*)(zz + ((size_t)r1.x << 7) + q * 4);
        float4 w2 = *(const float4*)(zz + ((size_t)r2.x << 7) + q * 4);
        float4 w3 = *(const float4*)(zz + ((size_t)r3.x << 7) + q * 4);
        float n0 = __int_as_float(r0.y), n1 = __int_as_float(r1.y);
        float n2 = __int_as_float(r2.y), n3 = __int_as_float(r3.y);
        a0 += n0 * w0.x + n1 * w1.x + n2 * w2.x + n3 * w3.x;
        a1 += n0 * w0.y + n1 * w1.y + n2 * w2.y + n3 * w3.y;
        a2 += n0 * w0.z + n1 * w1.z + n2 * w2.z + n3 * w3.z;
        a3 += n0 * w0.w + n1 * w1.w + n2 * w2.w + n3 * w3.w;
    }
    for (int e = ee + half; e < e1; e += 2) {
        int2 r = ebuf2[e];
        float nm = __int_as_float(r.y);
        float4 w = *(const float4*)(zz + ((size_t)r.x << 7) + q * 4);
        a0 += nm * w.x; a1 += nm * w.y; a2 += nm * w.z; a3 += nm * w.w;
    }
    a0 += __shfl_xor(a0, 32);
    a1 += __shfl_xor(a1, 32);
    a2 += __shfl_xor(a2, 32);
    a3 += __shfl_xor(a3, 32);

    if (half == 0) {
        float4 b = *(const float4*)(bias + q * 4);
        float4 o;
        o.x = di * a0 + b.x;
        o.y = di * a1 + b.y;
        o.z = di * a2 + b.z;
        o.w = di * a3 + b.w;
        *(float4*)(out + (size_t)i * 128 + q * 4) = o;
    }
}

// ---------- pooling (hierarchical; h2 now fp16) ----------
__global__ __launch_bounds__(128) void pool2_k(const __half* __restrict__ h2,
                                               const int* __restrict__ batch,
                                               float* __restrict__ pooled)
{
    int g = blockIdx.x;
    int c = blockIdx.y;
    int f = threadIdx.x;
    int bs = lowerb(batch, NN, g);
    int be = lowerb(batch, NN, g + 1);
    int len = be - bs;
    int cs = bs + (int)(((long long)len * c) / PCH);
    int ce = bs + (int)(((long long)len * (c + 1)) / PCH);
    float a = 0.f;
    for (int i = cs; i < ce; i++) a += __half2float(h2[(size_t)i * 128 + f]);
    if (ce > cs) atomicAdd(&pooled[(size_t)g * 128 + f], a);
}

// ---------- fused fc + decoder + W3 transform ----------
__global__ __launch_bounds__(128) void fcdec_k(const float* __restrict__ pooled,
                                               const float* __restrict__ fcW,   // [128][64]
                                               const float* __restrict__ fcb,
                                               const float* __restrict__ decW,  // [64][128]
                                               const float* __restrict__ decb,
                                               const float* __restrict__ W3,    // [128][128]
                                               float* __restrict__ lat_out,
                                               float* __restrict__ zz)
{
    __shared__ float lat[64];
    __shared__ float zs[128];
    int g = blockIdx.x, c = threadIdx.x;
    if (c < 64) {
        const float* p = pooled + (size_t)g * 128;
        float a = fcb[c];
        #pragma unroll 8
        for (int k = 0; k < 128; k++) a = fmaf(p[k], fcW[(size_t)k * 64 + c], a);
        a = fmaxf(a, 0.f);
        lat[c] = a;
        lat_out[(size_t)g * 64 + c] = a;
    }
    __syncthreads();
    {
        float a = decb[c];
        #pragma unroll 8
        for (int k = 0; k < 64; k++) a = fmaf(lat[k], decW[(size_t)k * 128 + c], a);
        zs[c] = fmaxf(a, 0.f);
    }
    __syncthreads();
    float o = 0.f;
    #pragma unroll 8
    for (int k = 0; k < 128; k++) o = fmaf(zs[k], W3[(size_t)k * 128 + c], o);
    zz[(size_t)g * 128 + c] = o;
}

extern "C" void kernel_launch(void* const* d_in, const int* in_sizes, int n_in,
                              void* d_out, int out_size, void* d_ws, size_t ws_size,
                              hipStream_t stream)
{
    const float* x     = (const float*)d_in[0];
    const int*   ei    = (const int*)d_in[1];
    const int*   batch = (const int*)d_in[2];
    const float* W1  = (const float*)d_in[3];
    const float* b1  = (const float*)d_in[4];
    const float* W2  = (const float*)d_in[5];
    const float* b2  = (const float*)d_in[6];
    const float* fcW = (const float*)d_in[7];
    const float* fcb = (const float*)d_in[8];
    const float* decW= (const float*)d_in[9];
    const float* decb= (const float*)d_in[10];
    const float* W3  = (const float*)d_in[11];
    const float* b3  = (const float*)d_in[12];

    char* ws = (char*)d_ws;
    size_t off = 0;
    auto alloc = [&](size_t bytes) -> char* {
        char* p = ws + off;
        off = (off + bytes + 255) & ~(size_t)255;
        return p;
    };
    float* dinv     = (float*)alloc((size_t)NN * 4);
    int*   rowptr   = (int*)alloc((size_t)(NN + 1) * 4);
    int*   bcur     = (int*)alloc((size_t)NB * 4);
    int*   bbase    = (int*)alloc((size_t)NB * 4);
    int*   ebuf     = (int*)alloc((size_t)EE * 4);           // CSR src indices (4B/edge)
    int2*  ebuf2    = (int2*)alloc((size_t)EE * 8);          // {batch[src], dinv[src]}
    float* pooled   = (float*)alloc((size_t)GG * 128 * 4);
    float* zz       = (float*)alloc((size_t)GG * 128 * 4);
    f16x8* whi1     = (f16x8*)alloc(2048 * 16);              // W1 hi frags (32KB)
    f16x8* wlo1     = (f16x8*)alloc(2048 * 16);
    f16x8* whi2     = (f16x8*)alloc(2048 * 16);
    f16x8* wlo2     = (f16x8*)alloc(2048 * 16);
    __half* A       = (__half*)alloc((size_t)NN * 128 * 2);  // pre-scaled transformed feats (fp16)
    __half* B       = (__half*)alloc((size_t)NN * 128 * 2);  // h1/h2 activations (fp16)
    int2*  eraw     = (int2*)alloc((size_t)NB * CAP * 8);    // binA output (own region now)

    float* recon_out = (float*)d_out;
    float* lat_out   = (float*)d_out + (size_t)NN * 128;

    prep_k<<<19, 256, 0, stream>>>(W1, W2, whi1, wlo1, whi2, wlo2, bcur, pooled);
    binA_k<<<ABLK, 512, 0, stream>>>(ei, bcur, eraw);
    scanb2_k<<<1, 512, 0, stream>>>(bcur, bbase, rowptr);
    binB_k<<<NB, 512, 0, stream>>>(eraw, bcur, bbase, rowptr, dinv, ebuf);

    int gblk = (NN + 127) / 128;   // 391
    // conv1: A = dinv .* (x @ W1) (fp16) ; h1 = relu(dinv.*(agg(A)) + b1) -> B (fp16)
    // aggh1 carries PBBB extra blocks that build ebuf2 (edge-parallel, no interaction)
    gemm_mfma3_k<<<gblk, 512, 0, stream>>>(x, whi1, wlo1, dinv, A, NN);
    aggh_k<<<NN + PBBB, 64, 0, stream>>>(A, rowptr, ebuf, dinv, b1, B, batch, ebuf2);
    // conv2: fp16-input GEMM (A-frag exact, 2 MFMAs/tile); h2 -> B (fp16)
    gemm_mfma2h_k<<<gblk, 512, 0, stream>>>(B, whi2, wlo2, dinv, A, NN);
    aggh_k<<<NN, 64, 0, stream>>>(A, rowptr, ebuf, dinv, b2, B, batch, ebuf2);
    // pool + fused fc/dec (latent out) + conv3
    pool2_k<<<dim3(GG, PCH), 128, 0, stream>>>(B, batch, pooled);
    fcdec_k<<<GG, 128, 0, stream>>>(pooled, fcW, fcb, decW, decb, W3, lat_out, zz);
    agg_out_k<<<NN, 64, 0, stream>>>(zz, batch, rowptr, ebuf2, dinv,
                                     b3, recon_out);
}

// Round 14
// 265.960 us; speedup vs baseline: 1.3592x; 1.0220x over previous
//
#include <hip/hip_runtime.h>
#include <hip/hip_fp16.h>

// Problem constants
static constexpr int NN   = 50000;
static constexpr int EE   = 800000;
static constexpr int GG   = 256;
static constexpr int PCH  = 16;                 // pooling chunks per graph
static constexpr int BK   = 128;                // targets per bucket
static constexpr int NB   = (NN + BK - 1) / BK; // 391 buckets (bucket = dst>>7)
static constexpr int CAP  = 4096;               // bucket region capacity (mean 2048, sigma 45)
static constexpr int CH   = 2048;               // edges per binA block
static constexpr int ABLK = (EE + CH - 1) / CH; // 391
static constexpr int PBBB = EE / 64;            // 12500 ebuf2-build blocks piggybacked on aggh1

typedef _Float16 f16;
typedef f16  f16x8 __attribute__((ext_vector_type(8)));
typedef float f32x4 __attribute__((ext_vector_type(4)));

// ---------- helpers ----------
__device__ __forceinline__ int lowerb(const int* __restrict__ b, int n, int v) {
    int lo = 0, hi = n;
    while (lo < hi) { int m = (lo + hi) >> 1; if (b[m] < v) lo = m + 1; else hi = m; }
    return lo;
}

__device__ __forceinline__ int pack_rec(int bg, float w) {
    __half h = __float2half(w);
    return bg | ((int)__builtin_bit_cast(unsigned short, h) << 16);
}
__device__ __forceinline__ float rec_w(int rec) {
    return __half2float(__builtin_bit_cast(__half, (unsigned short)((unsigned)rec >> 16)));
}

// ---------- fused prep: W1/W2 frag conversion + bcur init + pooled zeroing ----------
// frag (nt,ks,kq,m) = W^T[nt*16+m][ks*32+kq*8 .. +8)  at index ((nt*4+ks)*4+kq)*16+m
__global__ __launch_bounds__(256) void prep_k(const float* __restrict__ W1,
                                              const float* __restrict__ W2,
                                              f16x8* __restrict__ whi1, f16x8* __restrict__ wlo1,
                                              f16x8* __restrict__ whi2, f16x8* __restrict__ wlo2,
                                              int* __restrict__ bcur,
                                              float* __restrict__ pooled)
{
    int blk = blockIdx.x, t = threadIdx.x;
    if (blk < 16) {
        const float* W = (blk < 8) ? W1 : W2;
        f16x8* wh = (blk < 8) ? whi1 : whi2;
        f16x8* wl = (blk < 8) ? wlo1 : wlo2;
        int tid = (blk & 7) * 256 + t;      // 0..2047
        int m  = tid & 15;
        int kq = (tid >> 4) & 3;
        int ks = (tid >> 6) & 3;
        int nt = tid >> 8;
        int n  = nt * 16 + m;
        int k0 = ks * 32 + kq * 8;
        f16x8 h8, l8;
        #pragma unroll
        for (int u = 0; u < 8; u++) {
            float x = W[(size_t)(k0 + u) * 128 + n];
            f16 h = (f16)x;
            h8[u] = h;
            l8[u] = (f16)(x - (float)h);
        }
        wh[tid] = h8;
        wl[tid] = l8;
    } else if (blk == 16) {
        for (int b = t; b < NB; b += 256) bcur[b] = b * CAP;
    } else {
        float4* p = (float4*)pooled;        // GG*128 floats = 8192 float4
        for (int j = (blk - 17) * 256 + t; j < GG * 32; j += 512)
            p[j] = make_float4(0.f, 0.f, 0.f, 0.f);
    }
}

// Pass A: partition edges into fixed-capacity bucket regions, coalesced flush.
__global__ __launch_bounds__(512) void binA_k(const int* __restrict__ ei,
                                              int* __restrict__ bcur,
                                              int2* __restrict__ eraw)
{
    __shared__ int2  stage[CH];
    __shared__ short sbid[CH];
    __shared__ int   hist[NB], loff[NB], gbase[NB], lcur[NB];
    __shared__ int   sc[512];

    int tid = threadIdx.x;
    int e0 = blockIdx.x * CH;
    int n = EE - e0; if (n > CH) n = CH;

    for (int b = tid; b < NB; b += 512) hist[b] = 0;
    __syncthreads();

    int2 r[CH / 512];
    #pragma unroll
    for (int k = 0; k < CH / 512; k++) {
        int s = k * 512 + tid;
        if (s < n) {
            int src = ei[e0 + s];
            int dst = ei[EE + e0 + s];
            r[k] = make_int2(src, dst);
            atomicAdd(&hist[dst >> 7], 1);
        }
    }
    __syncthreads();
    int v = (tid < NB) ? hist[tid] : 0;
    sc[tid] = v;
    __syncthreads();
    #pragma unroll
    for (int off = 1; off < 512; off <<= 1) {
        int add = (tid >= off) ? sc[tid - off] : 0;
        __syncthreads();
        sc[tid] += add;
        __syncthreads();
    }
    if (tid < NB) { int ex = sc[tid] - v; loff[tid] = ex; lcur[tid] = ex; }
    __syncthreads();
    for (int b = tid; b < NB; b += 512)
        gbase[b] = atomicAdd(&bcur[b], hist[b]);
    __syncthreads();
    #pragma unroll
    for (int k = 0; k < CH / 512; k++) {
        int s = k * 512 + tid;
        if (s < n) {
            int b = r[k].y >> 7;
            int slot = atomicAdd(&lcur[b], 1);
            stage[slot] = r[k];
            sbid[slot]  = (short)b;
        }
    }
    __syncthreads();
    for (int s = tid; s < n; s += 512) {
        int b = sbid[s];
        eraw[(size_t)gbase[b] + (s - loff[b])] = stage[s];
    }
}

// Pass B: per bucket: compute own prefix base (LDS reduce over bcur), LDS hist ->
// rowptr + dinv, place src ints at exact CSR slots.
__global__ __launch_bounds__(512) void binB_k(const int2* __restrict__ eraw,
                                              const int* __restrict__ bcur,
                                              int* __restrict__ rowptr,
                                              float* __restrict__ dinv,
                                              int* __restrict__ ebuf)
{
    __shared__ int hist[BK], excl[BK], cur[BK];
    __shared__ int red[512];
    int b = blockIdx.x, tid = threadIdx.x;
    int t0 = b << 7;
    int lim = NN - t0; if (lim > BK) lim = BK;
    int tot = bcur[b] - b * CAP;

    // exclusive base = sum_{j<b} (bcur[j] - j*CAP)
    red[tid] = (tid < b) ? (bcur[tid] - tid * CAP) : 0;   // NB=391 < 512
    __syncthreads();
    #pragma unroll
    for (int off = 256; off > 0; off >>= 1) {
        if (tid < off) red[tid] += red[tid + off];
        __syncthreads();
    }
    int base = red[0];
    __syncthreads();

    const int2* er = eraw + (size_t)b * CAP;

    if (tid < BK) hist[tid] = 0;
    __syncthreads();
    for (int s = tid; s < tot; s += 512) atomicAdd(&hist[er[s].y & 127], 1);
    __syncthreads();
    if (tid < BK) excl[tid] = hist[tid];
    __syncthreads();
    #pragma unroll
    for (int off = 1; off < BK; off <<= 1) {
        int add = (tid >= off && tid < BK) ? excl[tid - off] : 0;
        __syncthreads();
        if (tid < BK) excl[tid] += add;
        __syncthreads();
    }
    if (tid < BK) {
        int ex = excl[tid] - hist[tid];
        cur[tid] = base + ex;
        if (tid < lim) {
            rowptr[t0 + tid] = base + ex;
            dinv[t0 + tid]   = rsqrtf((float)(hist[tid] + 1));   // deg + self-loop
        }
    }
    if (b == NB - 1 && tid == 0) rowptr[NN] = EE;
    __syncthreads();
    for (int s = tid; s < tot; s += 512) {
        int2 rec = er[s];
        int p = atomicAdd(&cur[rec.y & 127], 1);
        ebuf[p] = rec.x;
    }
}

// ---------- MFMA GEMM (f32 input): out = dinv .* (in @ W), fp16 out, split-precision ----
// 128 rows/block, 8 waves. hi table in 32KB LDS; lo from L2. 3 MFMAs/tile.
// C/D: col=lane&15, row=(lane>>4)*4+reg (HW-verified).
__global__ __launch_bounds__(512) void gemm_mfma3_k(const float* __restrict__ in,
                                                    const f16x8* __restrict__ whi_f,
                                                    const f16x8* __restrict__ wlo_f,
                                                    const float* __restrict__ dinv,
                                                    __half* __restrict__ out,
                                                    int rows)
{
    __shared__ __align__(16) f16x8 sh[2048];    // 32KB: hi frags, same indexing as table
    int tid  = threadIdx.x;
    #pragma unroll
    for (int u = 0; u < 4; u++) sh[u * 512 + tid] = whi_f[u * 512 + tid];
    __syncthreads();

    int lane = tid & 63;
    int wv   = tid >> 6;                   // 0..7
    int rB   = blockIdx.x * 128 + wv * 16;
    int m    = lane & 15;
    int kq   = lane >> 4;                  // 0..3
    int r    = rB + m;
    int rr   = (r < rows) ? r : (rows - 1);

    // A-frags: k = ks*32 + kq*8 + [0..8)
    f16x8 ahi[4], alo[4];
    const float* rp = in + (size_t)rr * 128 + kq * 8;
    #pragma unroll
    for (int ks = 0; ks < 4; ks++) {
        float4 p0 = *(const float4*)(rp + ks * 32);
        float4 p1 = *(const float4*)(rp + ks * 32 + 4);
        float xs[8] = {p0.x, p0.y, p0.z, p0.w, p1.x, p1.y, p1.z, p1.w};
        #pragma unroll
        for (int u = 0; u < 8; u++) {
            f16 h = (f16)xs[u];
            ahi[ks][u] = h;
            alo[ks][u] = (f16)(xs[u] - (float)h);
        }
    }

    f32x4 acc[8];
    #pragma unroll
    for (int n = 0; n < 8; n++) acc[n] = (f32x4){0.f, 0.f, 0.f, 0.f};

    #pragma unroll
    for (int nt = 0; nt < 8; nt++) {
        #pragma unroll
        for (int ks = 0; ks < 4; ks++) {
            int idx = ((nt * 4 + ks) * 4 + kq) * 16 + m;
            f16x8 bh = sh[idx];
            f16x8 bl = wlo_f[idx];
            acc[nt] = __builtin_amdgcn_mfma_f32_16x16x32_f16(ahi[ks], bh, acc[nt], 0, 0, 0);
            acc[nt] = __builtin_amdgcn_mfma_f32_16x16x32_f16(alo[ks], bh, acc[nt], 0, 0, 0);
            acc[nt] = __builtin_amdgcn_mfma_f32_16x16x32_f16(ahi[ks], bl, acc[nt], 0, 0, 0);
        }
    }

    // epilogue: row = kq*4 + reg, col = nt*16 + m; scale by dinv[row], store f16
    int   orow[4];
    float dv[4];
    #pragma unroll
    for (int j = 0; j < 4; j++) {
        int gr = rB + kq * 4 + j;
        orow[j] = gr;
        dv[j]   = (gr < rows) ? dinv[gr] : 0.f;
    }
    #pragma unroll
    for (int nt = 0; nt < 8; nt++) {
        int c = nt * 16 + m;
        #pragma unroll
        for (int j = 0; j < 4; j++) {
            if (orow[j] < rows)
                out[(size_t)orow[j] * 128 + c] = __float2half(acc[nt][j] * dv[j]);
        }
    }
}

// ---------- MFMA GEMM (fp16 input): A-frag exact in fp16 (lo(A)=0) -> only 2 MFMAs/tile ----
__global__ __launch_bounds__(512) void gemm_mfma2h_k(const __half* __restrict__ in,
                                                     const f16x8* __restrict__ whi_f,
                                                     const f16x8* __restrict__ wlo_f,
                                                     const float* __restrict__ dinv,
                                                     __half* __restrict__ out,
                                                     int rows)
{
    __shared__ __align__(16) f16x8 sh[2048];    // 32KB hi frags
    int tid  = threadIdx.x;
    #pragma unroll
    for (int u = 0; u < 4; u++) sh[u * 512 + tid] = whi_f[u * 512 + tid];
    __syncthreads();

    int lane = tid & 63;
    int wv   = tid >> 6;
    int rB   = blockIdx.x * 128 + wv * 16;
    int m    = lane & 15;
    int kq   = lane >> 4;
    int r    = rB + m;
    int rr   = (r < rows) ? r : (rows - 1);

    // A-frags: 8 contiguous fp16 at k = ks*32 + kq*8 (16B aligned)
    f16x8 ah[4];
    const f16* rp = (const f16*)in + (size_t)rr * 128 + kq * 8;
    #pragma unroll
    for (int ks = 0; ks < 4; ks++)
        ah[ks] = *(const f16x8*)(rp + ks * 32);

    f32x4 acc[8];
    #pragma unroll
    for (int n = 0; n < 8; n++) acc[n] = (f32x4){0.f, 0.f, 0.f, 0.f};

    #pragma unroll
    for (int nt = 0; nt < 8; nt++) {
        #pragma unroll
        for (int ks = 0; ks < 4; ks++) {
            int idx = ((nt * 4 + ks) * 4 + kq) * 16 + m;
            f16x8 bh = sh[idx];
            f16x8 bl = wlo_f[idx];
            acc[nt] = __builtin_amdgcn_mfma_f32_16x16x32_f16(ah[ks], bh, acc[nt], 0, 0, 0);
            acc[nt] = __builtin_amdgcn_mfma_f32_16x16x32_f16(ah[ks], bl, acc[nt], 0, 0, 0);
        }
    }

    int   orow[4];
    float dv[4];
    #pragma unroll
    for (int j = 0; j < 4; j++) {
        int gr = rB + kq * 4 + j;
        orow[j] = gr;
        dv[j]   = (gr < rows) ? dinv[gr] : 0.f;
    }
    #pragma unroll
    for (int nt = 0; nt < 8; nt++) {
        int c = nt * 16 + m;
        #pragma unroll
        for (int j = 0; j < 4; j++) {
            if (orow[j] < rows)
                out[(size_t)orow[j] * 128 + c] = __float2half(acc[nt][j] * dv[j]);
        }
    }
}

// ---------- aggregation gather body (PROVEN r8 version) ----------
__device__ __forceinline__ float4 gat4h(const __half* __restrict__ t, int s, int q)
{
    uint2 v = *(const uint2*)(t + ((size_t)s << 7) + q * 4);
    __half2 a = __builtin_bit_cast(__half2, v.x);
    __half2 b = __builtin_bit_cast(__half2, v.y);
    float2 fa = __half22float2(a), fb = __half22float2(b);
    return make_float4(fa.x, fa.y, fb.x, fb.y);
}

// core: accumulate sum_e t[src_e][q*4..q*4+4) + t[i][...] into a0..a3 (halves folded)
#define AGG_BODY                                                                 \
    int e0 = __builtin_amdgcn_readfirstlane(rowptr[i]);                          \
    int e1 = __builtin_amdgcn_readfirstlane(rowptr[i + 1]);                      \
    int deg = e1 - e0;                                                           \
    int idxsafe = (deg > 0) ? (e0 + min(lane, deg - 1)) : 0;                     \
    int myidx = ebuf[idxsafe];                                                   \
    float a0 = 0.f, a1 = 0.f, a2 = 0.f, a3 = 0.f;                                \
    if (half == 0) {                                                             \
        float4 v = gat4h(t, i, q);                                               \
        a0 = v.x; a1 = v.y; a2 = v.z; a3 = v.w;                                  \
    }                                                                            \
    int v   = min(deg, 64);                                                      \
    int c16 = v & ~15;                                                           \
    for (int j = half * 8; j < c16; j += 16) {                                   \
        int s0 = __shfl(myidx, j + 0), s1 = __shfl(myidx, j + 1);                \
        int s2 = __shfl(myidx, j + 2), s3 = __shfl(myidx, j + 3);                \
        int s4 = __shfl(myidx, j + 4), s5 = __shfl(myidx, j + 5);                \
        int s6 = __shfl(myidx, j + 6), s7 = __shfl(myidx, j + 7);                \
        float4 w0 = gat4h(t, s0, q);                                             \
        float4 w1 = gat4h(t, s1, q);                                             \
        float4 w2 = gat4h(t, s2, q);                                             \
        float4 w3 = gat4h(t, s3, q);                                             \
        float4 w4 = gat4h(t, s4, q);                                             \
        float4 w5 = gat4h(t, s5, q);                                             \
        float4 w6 = gat4h(t, s6, q);                                             \
        float4 w7 = gat4h(t, s7, q);                                             \
        a0 += w0.x + w1.x + w2.x + w3.x + w4.x + w5.x + w6.x + w7.x;             \
        a1 += w0.y + w1.y + w2.y + w3.y + w4.y + w5.y + w6.y + w7.y;             \
        a2 += w0.z + w1.z + w2.z + w3.z + w4.z + w5.z + w6.z + w7.z;             \
        a3 += w0.w + w1.w + w2.w + w3.w + w4.w + w5.w + w6.w + w7.w;             \
    }                                                                            \
    if (v - c16 >= 8) {                                                          \
        int j = c16 + half * 4;                                                  \
        int s0 = __shfl(myidx, j + 0), s1 = __shfl(myidx, j + 1);                \
        int s2 = __shfl(myidx, j + 2), s3 = __shfl(myidx, j + 3);                \
        float4 w0 = gat4h(t, s0, q);                                             \
        float4 w1 = gat4h(t, s1, q);                                             \
        float4 w2 = gat4h(t, s2, q);                                             \
        float4 w3 = gat4h(t, s3, q);                                             \
        a0 += w0.x + w1.x + w2.x + w3.x;                                         \
        a1 += w0.y + w1.y + w2.y + w3.y;                                         \
        a2 += w0.z + w1.z + w2.z + w3.z;                                         \
        a3 += w0.w + w1.w + w2.w + w3.w;                                         \
    }                                                                            \
    int done = c16 + ((v - c16) & 8);                                            \
    for (int j = done + half; j < v; j += 2) {                                   \
        int s = __shfl(myidx, j);                                                \
        float4 w = gat4h(t, s, q);                                               \
        a0 += w.x; a1 += w.y; a2 += w.z; a3 += w.w;                              \
    }                                                                            \
    for (int e = e0 + 64 + half; e < e1; e += 2) {                               \
        float4 w = gat4h(t, ebuf[e], q);                                         \
        a0 += w.x; a1 += w.y; a2 += w.z; a3 += w.w;                              \
    }                                                                            \
    a0 += __shfl_xor(a0, 32);                                                    \
    a1 += __shfl_xor(a1, 32);                                                    \
    a2 += __shfl_xor(a2, 32);                                                    \
    a3 += __shfl_xor(a3, 32);

// conv aggregation -> writes relu'd rows as fp16; blocks >= NN piggyback the ebuf2 build
__global__ __launch_bounds__(64) void aggh_k(const __half* __restrict__ t,
                                             const int* __restrict__ rowptr,
                                             const int* __restrict__ ebuf,
                                             const float* __restrict__ dinv,
                                             const float* __restrict__ bias,
                                             __half* __restrict__ out,
                                             const int* __restrict__ batch,
                                             int* __restrict__ ebuf2)
{
    int bid  = blockIdx.x;
    int lane = threadIdx.x;
    if (bid >= NN) {                      // piggybacked ebuf2 build: packed 4B records
        int e = (bid - NN) * 64 + lane;
        if (e < EE) {
            int src = ebuf[e];
            ebuf2[e] = pack_rec(batch[src], dinv[src]);
        }
        return;
    }
    int i    = bid;
    int half = lane >> 5;
    int q    = lane & 31;
    AGG_BODY
    if (half == 0) {
        float di = dinv[i];
        float4 b = *(const float4*)(bias + q * 4);
        float ox = fmaxf(di * a0 + b.x, 0.f);
        float oy = fmaxf(di * a1 + b.y, 0.f);
        float oz = fmaxf(di * a2 + b.z, 0.f);
        float ow = fmaxf(di * a3 + b.w, 0.f);
        __half2 h01 = __floats2half2_rn(ox, oy);
        __half2 h23 = __floats2half2_rn(oz, ow);
        uint2 u = make_uint2(__builtin_bit_cast(unsigned, h01),
                             __builtin_bit_cast(unsigned, h23));
        *(uint2*)(out + (size_t)i * 128 + q * 4) = u;
    }
}

// conv3 aggregation, paired-edge (r8 structure, 4B packed records {bg|f16(dinv)}):
// zz (131KB) L2-resident. Lane covers float4; halves process alternate edge-chunks.
__global__ __launch_bounds__(64) void agg_out_k(const float* __restrict__ zz,
                                                const int* __restrict__ batch,
                                                const int* __restrict__ rowptr,
                                                const int* __restrict__ ebuf2,
                                                const float* __restrict__ dinv,
                                                const float* __restrict__ bias,
                                                float* __restrict__ out)
{
    int i    = blockIdx.x;
    int lane = threadIdx.x;
    int half = lane >> 5;
    int q    = lane & 31;
    float di = dinv[i];

    float a0 = 0.f, a1 = 0.f, a2 = 0.f, a3 = 0.f;
    if (half == 0) {                     // self term: di * zz[batch[i]]
        float4 v = *(const float4*)(zz + ((size_t)batch[i] << 7) + q * 4);
        a0 = di * v.x; a1 = di * v.y; a2 = di * v.z; a3 = di * v.w;
    }

    int e0 = rowptr[i], e1 = rowptr[i + 1];
    int deg = e1 - e0;
    int full = deg & ~7;
    int ee = e0 + full;
    for (int e = e0 + half * 4; e < ee; e += 8) {
        int r0 = ebuf2[e],     r1 = ebuf2[e + 1];
        int r2 = ebuf2[e + 2], r3 = ebuf2[e + 3];
        float4 w0 = *(const float4*)(zz + ((size_t)(r0 & 0xffff) << 7) + q * 4);
        float4 w1 = *(const float4*)(zz + ((size_t)(r1 & 0xffff) << 7) + q * 4);
        float4 w2 = *(const float4*)(zz + ((size_t)(r2 & 0xffff) << 7) + q * 4);
        float4 w3 = *(const float4*)(zz + ((size_t)(r3 & 0xffff) << 7) + q * 4);
        float n0 = rec_w(r0), n1 = rec_w(r1);
        float n2 = rec_w(r2), n3 = rec_w(r3);
        a0 += n0 * w0.x + n1 * w1.x + n2 * w2.x + n3 * w3.x;
        a1 += n0 * w0.y + n1 * w1.y + n2 * w2.y + n3 * w3.y;
        a2 += n0 * w0.z + n1 * w1.z + n2 * w2.z + n3 * w3.z;
        a3 += n0 * w0.w + n1 * w1.w + n2 * w2.w + n3 * w3.w;
    }
    for (int e = ee + half; e < e1; e += 2) {
        int r = ebuf2[e];
        float nm = rec_w(r);
        float4 w = *(const float4*)(zz + ((size_t)(r & 0xffff) << 7) + q * 4);
        a0 += nm * w.x; a1 += nm * w.y; a2 += nm * w.z; a3 += nm * w.w;
    }
    a0 += __shfl_xor(a0, 32);
    a1 += __shfl_xor(a1, 32);
    a2 += __shfl_xor(a2, 32);
    a3 += __shfl_xor(a3, 32);

    if (half == 0) {
        float4 b = *(const float4*)(bias + q * 4);
        float4 o;
        o.x = di * a0 + b.x;
        o.y = di * a1 + b.y;
        o.z = di * a2 + b.z;
        o.w = di * a3 + b.w;
        *(float4*)(out + (size_t)i * 128 + q * 4) = o;
    }
}

// ---------- pooling (hierarchical; h2 fp16) ----------
__global__ __launch_bounds__(128) void pool2_k(const __half* __restrict__ h2,
                                               const int* __restrict__ batch,
                                               float* __restrict__ pooled)
{
    int g = blockIdx.x;
    int c = blockIdx.y;
    int f = threadIdx.x;
    int bs = lowerb(batch, NN, g);
    int be = lowerb(batch, NN, g + 1);
    int len = be - bs;
    int cs = bs + (int)(((long long)len * c) / PCH);
    int ce = bs + (int)(((long long)len * (c + 1)) / PCH);
    float a = 0.f;
    for (int i = cs; i < ce; i++) a += __half2float(h2[(size_t)i * 128 + f]);
    if (ce > cs) atomicAdd(&pooled[(size_t)g * 128 + f], a);
}

// ---------- fused fc + decoder + W3 transform ----------
__global__ __launch_bounds__(128) void fcdec_k(const float* __restrict__ pooled,
                                               const float* __restrict__ fcW,   // [128][64]
                                               const float* __restrict__ fcb,
                                               const float* __restrict__ decW,  // [64][128]
                                               const float* __restrict__ decb,
                                               const float* __restrict__ W3,    // [128][128]
                                               float* __restrict__ lat_out,
                                               float* __restrict__ zz)
{
    __shared__ float lat[64];
    __shared__ float zs[128];
    int g = blockIdx.x, c = threadIdx.x;
    if (c < 64) {
        const float* p = pooled + (size_t)g * 128;
        float a = fcb[c];
        #pragma unroll 8
        for (int k = 0; k < 128; k++) a = fmaf(p[k], fcW[(size_t)k * 64 + c], a);
        a = fmaxf(a, 0.f);
        lat[c] = a;
        lat_out[(size_t)g * 64 + c] = a;
    }
    __syncthreads();
    {
        float a = decb[c];
        #pragma unroll 8
        for (int k = 0; k < 64; k++) a = fmaf(lat[k], decW[(size_t)k * 128 + c], a);
        zs[c] = fmaxf(a, 0.f);
    }
    __syncthreads();
    float o = 0.f;
    #pragma unroll 8
    for (int k = 0; k < 128; k++) o = fmaf(zs[k], W3[(size_t)k * 128 + c], o);
    zz[(size_t)g * 128 + c] = o;
}

extern "C" void kernel_launch(void* const* d_in, const int* in_sizes, int n_in,
                              void* d_out, int out_size, void* d_ws, size_t ws_size,
                              hipStream_t stream)
{
    const float* x     = (const float*)d_in[0];
    const int*   ei    = (const int*)d_in[1];
    const int*   batch = (const int*)d_in[2];
    const float* W1  = (const float*)d_in[3];
    const float* b1  = (const float*)d_in[4];
    const float* W2  = (const float*)d_in[5];
    const float* b2  = (const float*)d_in[6];
    const float* fcW = (const float*)d_in[7];
    const float* fcb = (const float*)d_in[8];
    const float* decW= (const float*)d_in[9];
    const float* decb= (const float*)d_in[10];
    const float* W3  = (const float*)d_in[11];
    const float* b3  = (const float*)d_in[12];

    char* ws = (char*)d_ws;
    size_t off = 0;
    auto alloc = [&](size_t bytes) -> char* {
        char* p = ws + off;
        off = (off + bytes + 255) & ~(size_t)255;
        return p;
    };
    float* dinv     = (float*)alloc((size_t)NN * 4);
    int*   rowptr   = (int*)alloc((size_t)(NN + 1) * 4);
    int*   bcur     = (int*)alloc((size_t)NB * 4);
    int*   ebuf     = (int*)alloc((size_t)EE * 4);           // CSR src indices (4B/edge)
    int*   ebuf2    = (int*)alloc((size_t)EE * 4);           // packed {bg | f16(dinv)<<16}
    float* pooled   = (float*)alloc((size_t)GG * 128 * 4);
    float* zz       = (float*)alloc((size_t)GG * 128 * 4);
    f16x8* whi1     = (f16x8*)alloc(2048 * 16);              // W1 hi frags (32KB)
    f16x8* wlo1     = (f16x8*)alloc(2048 * 16);
    f16x8* whi2     = (f16x8*)alloc(2048 * 16);
    f16x8* wlo2     = (f16x8*)alloc(2048 * 16);
    __half* A       = (__half*)alloc((size_t)NN * 128 * 2);  // pre-scaled transformed feats (fp16)
    __half* B       = (__half*)alloc((size_t)NN * 128 * 2);  // h1/h2 activations (fp16)
    int2*  eraw     = (int2*)alloc((size_t)NB * CAP * 8);    // binA output

    float* recon_out = (float*)d_out;
    float* lat_out   = (float*)d_out + (size_t)NN * 128;

    prep_k<<<19, 256, 0, stream>>>(W1, W2, whi1, wlo1, whi2, wlo2, bcur, pooled);
    binA_k<<<ABLK, 512, 0, stream>>>(ei, bcur, eraw);
    binB_k<<<NB, 512, 0, stream>>>(eraw, bcur, rowptr, dinv, ebuf);

    int gblk = (NN + 127) / 128;   // 391
    // conv1: A = dinv .* (x @ W1) (fp16) ; h1 = relu(dinv.*(agg(A)) + b1) -> B (fp16)
    // aggh1 carries PBBB extra blocks that build ebuf2 (edge-parallel, no interaction)
    gemm_mfma3_k<<<gblk, 512, 0, stream>>>(x, whi1, wlo1, dinv, A, NN);
    aggh_k<<<NN + PBBB, 64, 0, stream>>>(A, rowptr, ebuf, dinv, b1, B, batch, ebuf2);
    // conv2: fp16-input GEMM (A-frag exact, 2 MFMAs/tile); h2 -> B (fp16)
    gemm_mfma2h_k<<<gblk, 512, 0, stream>>>(B, whi2, wlo2, dinv, A, NN);
    aggh_k<<<NN, 64, 0, stream>>>(A, rowptr, ebuf, dinv, b2, B, batch, ebuf2);
    // pool + fused fc/dec (latent out) + conv3
    pool2_k<<<dim3(GG, PCH), 128, 0, stream>>>(B, batch, pooled);
    fcdec_k<<<GG, 128, 0, stream>>>(pooled, fcW, fcb, decW, decb, W3, lat_out, zz);
    agg_out_k<<<NN, 64, 0, stream>>>(zz, batch, rowptr, ebuf2, dinv,
                                     b3, recon_out);
}

// Round 15
// 252.247 us; speedup vs baseline: 1.4331x; 1.0544x over previous
//
#include <hip/hip_runtime.h>
#include <hip/hip_fp16.h>

// Problem constants
static constexpr int NN   = 50000;
static constexpr int EE   = 800000;
static constexpr int GG   = 256;
static constexpr int PCH  = 16;                 // pooling chunks per graph
static constexpr int BK   = 128;                // targets per bucket
static constexpr int NB   = (NN + BK - 1) / BK; // 391 buckets (bucket = dst>>7)
static constexpr int CAP  = 4096;               // bucket region capacity (mean 2048, sigma 45)
static constexpr int CH   = 2048;               // edges per binA block
static constexpr int ABLK = (EE + CH - 1) / CH; // 391
static constexpr int GBLK = (NN + 127) / 128;   // 391 gemm blocks
static constexpr int PBBB = EE / 64;            // 12500 ebuf2-build blocks piggybacked on aggh1

typedef _Float16 f16;
typedef f16  f16x8 __attribute__((ext_vector_type(8)));
typedef float f32x4 __attribute__((ext_vector_type(4)));

// ---------- helpers ----------
__device__ __forceinline__ int lowerb(const int* __restrict__ b, int n, int v) {
    int lo = 0, hi = n;
    while (lo < hi) { int m = (lo + hi) >> 1; if (b[m] < v) lo = m + 1; else hi = m; }
    return lo;
}

__device__ __forceinline__ int pack_rec(int bg, float w) {
    __half h = __float2half(w);
    return bg | ((int)__builtin_bit_cast(unsigned short, h) << 16);
}
__device__ __forceinline__ float rec_w(int rec) {
    return __half2float(__builtin_bit_cast(__half, (unsigned short)((unsigned)rec >> 16)));
}

// ---------- fused prep: W1/W2 frag conversion + bcur init + pooled zeroing ----------
// frag (nt,ks,kq,m) = W^T[nt*16+m][ks*32+kq*8 .. +8)  at index ((nt*4+ks)*4+kq)*16+m
__global__ __launch_bounds__(256) void prep_k(const float* __restrict__ W1,
                                              const float* __restrict__ W2,
                                              f16x8* __restrict__ whi1, f16x8* __restrict__ wlo1,
                                              f16x8* __restrict__ whi2, f16x8* __restrict__ wlo2,
                                              int* __restrict__ bcur,
                                              float* __restrict__ pooled)
{
    int blk = blockIdx.x, t = threadIdx.x;
    if (blk < 16) {
        const float* W = (blk < 8) ? W1 : W2;
        f16x8* wh = (blk < 8) ? whi1 : whi2;
        f16x8* wl = (blk < 8) ? wlo1 : wlo2;
        int tid = (blk & 7) * 256 + t;      // 0..2047
        int m  = tid & 15;
        int kq = (tid >> 4) & 3;
        int ks = (tid >> 6) & 3;
        int nt = tid >> 8;
        int n  = nt * 16 + m;
        int k0 = ks * 32 + kq * 8;
        f16x8 h8, l8;
        #pragma unroll
        for (int u = 0; u < 8; u++) {
            float x = W[(size_t)(k0 + u) * 128 + n];
            f16 h = (f16)x;
            h8[u] = h;
            l8[u] = (f16)(x - (float)h);
        }
        wh[tid] = h8;
        wl[tid] = l8;
    } else if (blk == 16) {
        for (int b = t; b < NB; b += 256) bcur[b] = b * CAP;
    } else {
        float4* p = (float4*)pooled;        // GG*128 floats = 8192 float4
        for (int j = (blk - 17) * 256 + t; j < GG * 32; j += 512)
            p[j] = make_float4(0.f, 0.f, 0.f, 0.f);
    }
}

// ---------- fused: gemm1 (unscaled, no dinv dep) ∥ binA (edge partition) ----------
// blocks [0,GBLK): t1 = x @ W1 -> A (fp16, UNSCALED; conv1 norm applied in agghw).
// blocks [GBLK, GBLK+ABLK): binA partition. LDS unioned in one 32KB char array.
__global__ __launch_bounds__(512) void gemm1_binA_k(const float* __restrict__ in,
                                                    const f16x8* __restrict__ whi_f,
                                                    const f16x8* __restrict__ wlo_f,
                                                    __half* __restrict__ out,
                                                    const int* __restrict__ ei,
                                                    int* __restrict__ bcur,
                                                    int2* __restrict__ eraw)
{
    __shared__ __align__(16) char smem[32768];
    int tid = threadIdx.x;

    if (blockIdx.x < GBLK) {
        // ---- gemm part (r14 gemm_mfma3_k minus dinv scaling) ----
        f16x8* sh = (f16x8*)smem;
        #pragma unroll
        for (int u = 0; u < 4; u++) sh[u * 512 + tid] = whi_f[u * 512 + tid];
        __syncthreads();

        int lane = tid & 63;
        int wv   = tid >> 6;
        int rB   = blockIdx.x * 128 + wv * 16;
        int m    = lane & 15;
        int kq   = lane >> 4;
        int r    = rB + m;
        int rr   = (r < NN) ? r : (NN - 1);

        f16x8 ahi[4], alo[4];
        const float* rp = in + (size_t)rr * 128 + kq * 8;
        #pragma unroll
        for (int ks = 0; ks < 4; ks++) {
            float4 p0 = *(const float4*)(rp + ks * 32);
            float4 p1 = *(const float4*)(rp + ks * 32 + 4);
            float xs[8] = {p0.x, p0.y, p0.z, p0.w, p1.x, p1.y, p1.z, p1.w};
            #pragma unroll
            for (int u = 0; u < 8; u++) {
                f16 h = (f16)xs[u];
                ahi[ks][u] = h;
                alo[ks][u] = (f16)(xs[u] - (float)h);
            }
        }

        f32x4 acc[8];
        #pragma unroll
        for (int n = 0; n < 8; n++) acc[n] = (f32x4){0.f, 0.f, 0.f, 0.f};

        #pragma unroll
        for (int nt = 0; nt < 8; nt++) {
            #pragma unroll
            for (int ks = 0; ks < 4; ks++) {
                int idx = ((nt * 4 + ks) * 4 + kq) * 16 + m;
                f16x8 bh = sh[idx];
                f16x8 bl = wlo_f[idx];
                acc[nt] = __builtin_amdgcn_mfma_f32_16x16x32_f16(ahi[ks], bh, acc[nt], 0, 0, 0);
                acc[nt] = __builtin_amdgcn_mfma_f32_16x16x32_f16(alo[ks], bh, acc[nt], 0, 0, 0);
                acc[nt] = __builtin_amdgcn_mfma_f32_16x16x32_f16(ahi[ks], bl, acc[nt], 0, 0, 0);
            }
        }

        #pragma unroll
        for (int nt = 0; nt < 8; nt++) {
            int c = nt * 16 + m;
            #pragma unroll
            for (int j = 0; j < 4; j++) {
                int gr = rB + kq * 4 + j;
                if (gr < NN)
                    out[(size_t)gr * 128 + c] = __float2half(acc[nt][j]);
            }
        }
        return;
    }

    // ---- binA part (r14 binA_k, LDS pointer-aliased) ----
    int2*  stage = (int2*)smem;                 // 2048 * 8  = 16384
    short* sbid  = (short*)(smem + 16384);      // 2048 * 2  =  4096
    int*   hist  = (int*)(smem + 20480);        // NB * 4
    int*   loff  = hist + NB;
    int*   gbase = loff + NB;
    int*   lcur  = gbase + NB;
    int*   sc    = (int*)(smem + 26736);        // 512 * 4

    int b0 = blockIdx.x - GBLK;
    int e0 = b0 * CH;
    int n = EE - e0; if (n > CH) n = CH;

    for (int b = tid; b < NB; b += 512) hist[b] = 0;
    __syncthreads();

    int2 r[CH / 512];
    #pragma unroll
    for (int k = 0; k < CH / 512; k++) {
        int s = k * 512 + tid;
        if (s < n) {
            int src = ei[e0 + s];
            int dst = ei[EE + e0 + s];
            r[k] = make_int2(src, dst);
            atomicAdd(&hist[dst >> 7], 1);
        }
    }
    __syncthreads();
    int v = (tid < NB) ? hist[tid] : 0;
    sc[tid] = v;
    __syncthreads();
    #pragma unroll
    for (int off = 1; off < 512; off <<= 1) {
        int add = (tid >= off) ? sc[tid - off] : 0;
        __syncthreads();
        sc[tid] += add;
        __syncthreads();
    }
    if (tid < NB) { int ex = sc[tid] - v; loff[tid] = ex; lcur[tid] = ex; }
    __syncthreads();
    for (int b = tid; b < NB; b += 512)
        gbase[b] = atomicAdd(&bcur[b], hist[b]);
    __syncthreads();
    #pragma unroll
    for (int k = 0; k < CH / 512; k++) {
        int s = k * 512 + tid;
        if (s < n) {
            int b = r[k].y >> 7;
            int slot = atomicAdd(&lcur[b], 1);
            stage[slot] = r[k];
            sbid[slot]  = (short)b;
        }
    }
    __syncthreads();
    for (int s = tid; s < n; s += 512) {
        int b = sbid[s];
        eraw[(size_t)gbase[b] + (s - loff[b])] = stage[s];
    }
}

// Pass B: per bucket: compute own prefix base (LDS reduce over bcur), LDS hist ->
// rowptr + dinv, place src ints at exact CSR slots.
__global__ __launch_bounds__(512) void binB_k(const int2* __restrict__ eraw,
                                              const int* __restrict__ bcur,
                                              int* __restrict__ rowptr,
                                              float* __restrict__ dinv,
                                              int* __restrict__ ebuf)
{
    __shared__ int hist[BK], excl[BK], cur[BK];
    __shared__ int red[512];
    int b = blockIdx.x, tid = threadIdx.x;
    int t0 = b << 7;
    int lim = NN - t0; if (lim > BK) lim = BK;
    int tot = bcur[b] - b * CAP;

    // exclusive base = sum_{j<b} (bcur[j] - j*CAP)
    red[tid] = (tid < b) ? (bcur[tid] - tid * CAP) : 0;   // NB=391 < 512
    __syncthreads();
    #pragma unroll
    for (int off = 256; off > 0; off >>= 1) {
        if (tid < off) red[tid] += red[tid + off];
        __syncthreads();
    }
    int base = red[0];
    __syncthreads();

    const int2* er = eraw + (size_t)b * CAP;

    if (tid < BK) hist[tid] = 0;
    __syncthreads();
    for (int s = tid; s < tot; s += 512) atomicAdd(&hist[er[s].y & 127], 1);
    __syncthreads();
    if (tid < BK) excl[tid] = hist[tid];
    __syncthreads();
    #pragma unroll
    for (int off = 1; off < BK; off <<= 1) {
        int add = (tid >= off && tid < BK) ? excl[tid - off] : 0;
        __syncthreads();
        if (tid < BK) excl[tid] += add;
        __syncthreads();
    }
    if (tid < BK) {
        int ex = excl[tid] - hist[tid];
        cur[tid] = base + ex;
        if (tid < lim) {
            rowptr[t0 + tid] = base + ex;
            dinv[t0 + tid]   = rsqrtf((float)(hist[tid] + 1));   // deg + self-loop
        }
    }
    if (b == NB - 1 && tid == 0) rowptr[NN] = EE;
    __syncthreads();
    for (int s = tid; s < tot; s += 512) {
        int2 rec = er[s];
        int p = atomicAdd(&cur[rec.y & 127], 1);
        ebuf[p] = rec.x;
    }
}

// ---------- MFMA GEMM (fp16 input): A-frag exact in fp16 (lo(A)=0) -> only 2 MFMAs/tile ----
// dinv-scaled epilogue (conv2 path).
__global__ __launch_bounds__(512) void gemm_mfma2h_k(const __half* __restrict__ in,
                                                     const f16x8* __restrict__ whi_f,
                                                     const f16x8* __restrict__ wlo_f,
                                                     const float* __restrict__ dinv,
                                                     __half* __restrict__ out,
                                                     int rows)
{
    __shared__ __align__(16) f16x8 sh[2048];    // 32KB hi frags
    int tid  = threadIdx.x;
    #pragma unroll
    for (int u = 0; u < 4; u++) sh[u * 512 + tid] = whi_f[u * 512 + tid];
    __syncthreads();

    int lane = tid & 63;
    int wv   = tid >> 6;
    int rB   = blockIdx.x * 128 + wv * 16;
    int m    = lane & 15;
    int kq   = lane >> 4;
    int r    = rB + m;
    int rr   = (r < rows) ? r : (rows - 1);

    // A-frags: 8 contiguous fp16 at k = ks*32 + kq*8 (16B aligned)
    f16x8 ah[4];
    const f16* rp = (const f16*)in + (size_t)rr * 128 + kq * 8;
    #pragma unroll
    for (int ks = 0; ks < 4; ks++)
        ah[ks] = *(const f16x8*)(rp + ks * 32);

    f32x4 acc[8];
    #pragma unroll
    for (int n = 0; n < 8; n++) acc[n] = (f32x4){0.f, 0.f, 0.f, 0.f};

    #pragma unroll
    for (int nt = 0; nt < 8; nt++) {
        #pragma unroll
        for (int ks = 0; ks < 4; ks++) {
            int idx = ((nt * 4 + ks) * 4 + kq) * 16 + m;
            f16x8 bh = sh[idx];
            f16x8 bl = wlo_f[idx];
            acc[nt] = __builtin_amdgcn_mfma_f32_16x16x32_f16(ah[ks], bh, acc[nt], 0, 0, 0);
            acc[nt] = __builtin_amdgcn_mfma_f32_16x16x32_f16(ah[ks], bl, acc[nt], 0, 0, 0);
        }
    }

    int   orow[4];
    float dv[4];
    #pragma unroll
    for (int j = 0; j < 4; j++) {
        int gr = rB + kq * 4 + j;
        orow[j] = gr;
        dv[j]   = (gr < rows) ? dinv[gr] : 0.f;
    }
    #pragma unroll
    for (int nt = 0; nt < 8; nt++) {
        int c = nt * 16 + m;
        #pragma unroll
        for (int j = 0; j < 4; j++) {
            if (orow[j] < rows)
                out[(size_t)orow[j] * 128 + c] = __float2half(acc[nt][j] * dv[j]);
        }
    }
}

// ---------- aggregation gather helper ----------
__device__ __forceinline__ float4 gat4h(const __half* __restrict__ t, int s, int q)
{
    uint2 v = *(const uint2*)(t + ((size_t)s << 7) + q * 4);
    __half2 a = __builtin_bit_cast(__half2, v.x);
    __half2 b = __builtin_bit_cast(__half2, v.y);
    float2 fa = __half22float2(a), fb = __half22float2(b);
    return make_float4(fa.x, fa.y, fb.x, fb.y);
}

// ---------- UNWEIGHTED gather body (PROVEN r8): sum_e t[src_e] + t[i] ----------
#define AGG_BODY                                                                 \
    int e0 = __builtin_amdgcn_readfirstlane(rowptr[i]);                          \
    int e1 = __builtin_amdgcn_readfirstlane(rowptr[i + 1]);                      \
    int deg = e1 - e0;                                                           \
    int idxsafe = (deg > 0) ? (e0 + min(lane, deg - 1)) : 0;                     \
    int myidx = ebuf[idxsafe];                                                   \
    float a0 = 0.f, a1 = 0.f, a2 = 0.f, a3 = 0.f;                                \
    if (half == 0) {                                                             \
        float4 v = gat4h(t, i, q);                                               \
        a0 = v.x; a1 = v.y; a2 = v.z; a3 = v.w;                                  \
    }                                                                            \
    int v   = min(deg, 64);                                                      \
    int c16 = v & ~15;                                                           \
    for (int j = half * 8; j < c16; j += 16) {                                   \
        int s0 = __shfl(myidx, j + 0), s1 = __shfl(myidx, j + 1);                \
        int s2 = __shfl(myidx, j + 2), s3 = __shfl(myidx, j + 3);                \
        int s4 = __shfl(myidx, j + 4), s5 = __shfl(myidx, j + 5);                \
        int s6 = __shfl(myidx, j + 6), s7 = __shfl(myidx, j + 7);                \
        float4 w0 = gat4h(t, s0, q);                                             \
        float4 w1 = gat4h(t, s1, q);                                             \
        float4 w2 = gat4h(t, s2, q);                                             \
        float4 w3 = gat4h(t, s3, q);                                             \
        float4 w4 = gat4h(t, s4, q);                                             \
        float4 w5 = gat4h(t, s5, q);                                             \
        float4 w6 = gat4h(t, s6, q);                                             \
        float4 w7 = gat4h(t, s7, q);                                             \
        a0 += w0.x + w1.x + w2.x + w3.x + w4.x + w5.x + w6.x + w7.x;             \
        a1 += w0.y + w1.y + w2.y + w3.y + w4.y + w5.y + w6.y + w7.y;             \
        a2 += w0.z + w1.z + w2.z + w3.z + w4.z + w5.z + w6.z + w7.z;             \
        a3 += w0.w + w1.w + w2.w + w3.w + w4.w + w5.w + w6.w + w7.w;             \
    }                                                                            \
    if (v - c16 >= 8) {                                                          \
        int j = c16 + half * 4;                                                  \
        int s0 = __shfl(myidx, j + 0), s1 = __shfl(myidx, j + 1);                \
        int s2 = __shfl(myidx, j + 2), s3 = __shfl(myidx, j + 3);                \
        float4 w0 = gat4h(t, s0, q);                                             \
        float4 w1 = gat4h(t, s1, q);                                             \
        float4 w2 = gat4h(t, s2, q);                                             \
        float4 w3 = gat4h(t, s3, q);                                             \
        a0 += w0.x + w1.x + w2.x + w3.x;                                         \
        a1 += w0.y + w1.y + w2.y + w3.y;                                         \
        a2 += w0.z + w1.z + w2.z + w3.z;                                         \
        a3 += w0.w + w1.w + w2.w + w3.w;                                         \
    }                                                                            \
    int done = c16 + ((v - c16) & 8);                                            \
    for (int j = done + half; j < v; j += 2) {                                   \
        int s = __shfl(myidx, j);                                                \
        float4 w = gat4h(t, s, q);                                               \
        a0 += w.x; a1 += w.y; a2 += w.z; a3 += w.w;                              \
    }                                                                            \
    for (int e = e0 + 64 + half; e < e1; e += 2) {                               \
        float4 w = gat4h(t, ebuf[e], q);                                         \
        a0 += w.x; a1 += w.y; a2 += w.z; a3 += w.w;                              \
    }                                                                            \
    a0 += __shfl_xor(a0, 32);                                                    \
    a1 += __shfl_xor(a1, 32);                                                    \
    a2 += __shfl_xor(a2, 32);                                                    \
    a3 += __shfl_xor(a3, 32);

// conv2 aggregation (PROVEN): input pre-scaled; writes relu'd fp16 rows; piggyback inert
__global__ __launch_bounds__(64) void aggh_k(const __half* __restrict__ t,
                                             const int* __restrict__ rowptr,
                                             const int* __restrict__ ebuf,
                                             const float* __restrict__ dinv,
                                             const float* __restrict__ bias,
                                             __half* __restrict__ out,
                                             const int* __restrict__ batch,
                                             int* __restrict__ ebuf2)
{
    int bid  = blockIdx.x;
    int lane = threadIdx.x;
    if (bid >= NN) {
        int e = (bid - NN) * 64 + lane;
        if (e < EE) {
            int src = ebuf[e];
            ebuf2[e] = pack_rec(batch[src], dinv[src]);
        }
        return;
    }
    int i    = bid;
    int half = lane >> 5;
    int q    = lane & 31;
    AGG_BODY
    if (half == 0) {
        float di = dinv[i];
        float4 b = *(const float4*)(bias + q * 4);
        float ox = fmaxf(di * a0 + b.x, 0.f);
        float oy = fmaxf(di * a1 + b.y, 0.f);
        float oz = fmaxf(di * a2 + b.z, 0.f);
        float ow = fmaxf(di * a3 + b.w, 0.f);
        __half2 h01 = __floats2half2_rn(ox, oy);
        __half2 h23 = __floats2half2_rn(oz, ow);
        uint2 u = make_uint2(__builtin_bit_cast(unsigned, h01),
                             __builtin_bit_cast(unsigned, h23));
        *(uint2*)(out + (size_t)i * 128 + q * 4) = u;
    }
}

// conv1 aggregation, WEIGHTED (A unscaled): h1 = relu(di*(sum dinv[s]*t[s] + di*t[i]) + b)
// Same structure as AGG_BODY; weights bulk-loaded as dinv[myidx] and shfl'd with indices.
// Blocks >= NN piggyback the ebuf2 build.
__global__ __launch_bounds__(64) void agghw_k(const __half* __restrict__ t,
                                              const int* __restrict__ rowptr,
                                              const int* __restrict__ ebuf,
                                              const float* __restrict__ dinv,
                                              const float* __restrict__ bias,
                                              __half* __restrict__ out,
                                              const int* __restrict__ batch,
                                              int* __restrict__ ebuf2)
{
    int bid  = blockIdx.x;
    int lane = threadIdx.x;
    if (bid >= NN) {
        int e = (bid - NN) * 64 + lane;
        if (e < EE) {
            int src = ebuf[e];
            ebuf2[e] = pack_rec(batch[src], dinv[src]);
        }
        return;
    }
    int i    = bid;
    int half = lane >> 5;
    int q    = lane & 31;
    float di = dinv[i];

    int e0 = __builtin_amdgcn_readfirstlane(rowptr[i]);
    int e1 = __builtin_amdgcn_readfirstlane(rowptr[i + 1]);
    int deg = e1 - e0;
    int idxsafe = (deg > 0) ? (e0 + min(lane, deg - 1)) : 0;
    int myidx = ebuf[idxsafe];
    float myw = dinv[myidx];              // L2-resident 200KB table

    float a0 = 0.f, a1 = 0.f, a2 = 0.f, a3 = 0.f;
    if (half == 0) {                      // self term weight = di (inside the sum)
        float4 sv = gat4h(t, i, q);
        a0 = di * sv.x; a1 = di * sv.y; a2 = di * sv.z; a3 = di * sv.w;
    }

    int v   = min(deg, 64);
    int c16 = v & ~15;
    for (int j = half * 8; j < c16; j += 16) {
        int s0 = __shfl(myidx, j + 0), s1 = __shfl(myidx, j + 1);
        int s2 = __shfl(myidx, j + 2), s3 = __shfl(myidx, j + 3);
        int s4 = __shfl(myidx, j + 4), s5 = __shfl(myidx, j + 5);
        int s6 = __shfl(myidx, j + 6), s7 = __shfl(myidx, j + 7);
        float n0 = __shfl(myw, j + 0), n1 = __shfl(myw, j + 1);
        float n2 = __shfl(myw, j + 2), n3 = __shfl(myw, j + 3);
        float n4 = __shfl(myw, j + 4), n5 = __shfl(myw, j + 5);
        float n6 = __shfl(myw, j + 6), n7 = __shfl(myw, j + 7);
        float4 w0 = gat4h(t, s0, q);
        float4 w1 = gat4h(t, s1, q);
        float4 w2 = gat4h(t, s2, q);
        float4 w3 = gat4h(t, s3, q);
        float4 w4 = gat4h(t, s4, q);
        float4 w5 = gat4h(t, s5, q);
        float4 w6 = gat4h(t, s6, q);
        float4 w7 = gat4h(t, s7, q);
        a0 += n0 * w0.x + n1 * w1.x + n2 * w2.x + n3 * w3.x
            + n4 * w4.x + n5 * w5.x + n6 * w6.x + n7 * w7.x;
        a1 += n0 * w0.y + n1 * w1.y + n2 * w2.y + n3 * w3.y
            + n4 * w4.y + n5 * w5.y + n6 * w6.y + n7 * w7.y;
        a2 += n0 * w0.z + n1 * w1.z + n2 * w2.z + n3 * w3.z
            + n4 * w4.z + n5 * w5.z + n6 * w6.z + n7 * w7.z;
        a3 += n0 * w0.w + n1 * w1.w + n2 * w2.w + n3 * w3.w
            + n4 * w4.w + n5 * w5.w + n6 * w6.w + n7 * w7.w;
    }
    if (v - c16 >= 8) {
        int j = c16 + half * 4;
        int s0 = __shfl(myidx, j + 0), s1 = __shfl(myidx, j + 1);
        int s2 = __shfl(myidx, j + 2), s3 = __shfl(myidx, j + 3);
        float n0 = __shfl(myw, j + 0), n1 = __shfl(myw, j + 1);
        float n2 = __shfl(myw, j + 2), n3 = __shfl(myw, j + 3);
        float4 w0 = gat4h(t, s0, q);
        float4 w1 = gat4h(t, s1, q);
        float4 w2 = gat4h(t, s2, q);
        float4 w3 = gat4h(t, s3, q);
        a0 += n0 * w0.x + n1 * w1.x + n2 * w2.x + n3 * w3.x;
        a1 += n0 * w0.y + n1 * w1.y + n2 * w2.y + n3 * w3.y;
        a2 += n0 * w0.z + n1 * w1.z + n2 * w2.z + n3 * w3.z;
        a3 += n0 * w0.w + n1 * w1.w + n2 * w2.w + n3 * w3.w;
    }
    int done = c16 + ((v - c16) & 8);
    for (int j = done + half; j < v; j += 2) {
        int s = __shfl(myidx, j);
        float nm = __shfl(myw, j);
        float4 w = gat4h(t, s, q);
        a0 += nm * w.x; a1 += nm * w.y; a2 += nm * w.z; a3 += nm * w.w;
    }
    for (int e = e0 + 64 + half; e < e1; e += 2) {   // rare deg>64 overflow
        int s = ebuf[e];
        float nm = dinv[s];
        float4 w = gat4h(t, s, q);
        a0 += nm * w.x; a1 += nm * w.y; a2 += nm * w.z; a3 += nm * w.w;
    }
    a0 += __shfl_xor(a0, 32);
    a1 += __shfl_xor(a1, 32);
    a2 += __shfl_xor(a2, 32);
    a3 += __shfl_xor(a3, 32);

    if (half == 0) {
        float4 b = *(const float4*)(bias + q * 4);
        float ox = fmaxf(di * a0 + b.x, 0.f);
        float oy = fmaxf(di * a1 + b.y, 0.f);
        float oz = fmaxf(di * a2 + b.z, 0.f);
        float ow = fmaxf(di * a3 + b.w, 0.f);
        __half2 h01 = __floats2half2_rn(ox, oy);
        __half2 h23 = __floats2half2_rn(oz, ow);
        uint2 u = make_uint2(__builtin_bit_cast(unsigned, h01),
                             __builtin_bit_cast(unsigned, h23));
        *(uint2*)(out + (size_t)i * 128 + q * 4) = u;
    }
}

// conv3 aggregation: weighted bulk-index body over fp16 zz (256B rows, L2-resident).
// Records packed {bg | f16(dinv[src])<<16}; out f32.
__global__ __launch_bounds__(64) void agg_out_k(const __half* __restrict__ zzh,
                                                const int* __restrict__ batch,
                                                const int* __restrict__ rowptr,
                                                const int* __restrict__ ebuf2,
                                                const float* __restrict__ dinv,
                                                const float* __restrict__ bias,
                                                float* __restrict__ out)
{
    int i    = blockIdx.x;
    int lane = threadIdx.x;
    int half = lane >> 5;
    int q    = lane & 31;
    float di = dinv[i];

    int e0 = __builtin_amdgcn_readfirstlane(rowptr[i]);
    int e1 = __builtin_amdgcn_readfirstlane(rowptr[i + 1]);
    int deg = e1 - e0;
    int idxsafe = (deg > 0) ? (e0 + min(lane, deg - 1)) : 0;
    int myrec = ebuf2[idxsafe];

    float a0 = 0.f, a1 = 0.f, a2 = 0.f, a3 = 0.f;
    if (half == 0) {                      // self term weight = di
        float4 sv = gat4h(zzh, batch[i], q);
        a0 = di * sv.x; a1 = di * sv.y; a2 = di * sv.z; a3 = di * sv.w;
    }

    int v   = min(deg, 64);
    int c16 = v & ~15;
    for (int j = half * 8; j < c16; j += 16) {
        int r0 = __shfl(myrec, j + 0), r1 = __shfl(myrec, j + 1);
        int r2 = __shfl(myrec, j + 2), r3 = __shfl(myrec, j + 3);
        int r4 = __shfl(myrec, j + 4), r5 = __shfl(myrec, j + 5);
        int r6 = __shfl(myrec, j + 6), r7 = __shfl(myrec, j + 7);
        float4 w0 = gat4h(zzh, r0 & 0xffff, q);
        float4 w1 = gat4h(zzh, r1 & 0xffff, q);
        float4 w2 = gat4h(zzh, r2 & 0xffff, q);
        float4 w3 = gat4h(zzh, r3 & 0xffff, q);
        float4 w4 = gat4h(zzh, r4 & 0xffff, q);
        float4 w5 = gat4h(zzh, r5 & 0xffff, q);
        float4 w6 = gat4h(zzh, r6 & 0xffff, q);
        float4 w7 = gat4h(zzh, r7 & 0xffff, q);
        float n0 = rec_w(r0), n1 = rec_w(r1), n2 = rec_w(r2), n3 = rec_w(r3);
        float n4 = rec_w(r4), n5 = rec_w(r5), n6 = rec_w(r6), n7 = rec_w(r7);
        a0 += n0 * w0.x + n1 * w1.x + n2 * w2.x + n3 * w3.x
            + n4 * w4.x + n5 * w5.x + n6 * w6.x + n7 * w7.x;
        a1 += n0 * w0.y + n1 * w1.y + n2 * w2.y + n3 * w3.y
            + n4 * w4.y + n5 * w5.y + n6 * w6.y + n7 * w7.y;
        a2 += n0 * w0.z + n1 * w1.z + n2 * w2.z + n3 * w3.z
            + n4 * w4.z + n5 * w5.z + n6 * w6.z + n7 * w7.z;
        a3 += n0 * w0.w + n1 * w1.w + n2 * w2.w + n3 * w3.w
            + n4 * w4.w + n5 * w5.w + n6 * w6.w + n7 * w7.w;
    }
    if (v - c16 >= 8) {
        int j = c16 + half * 4;
        int r0 = __shfl(myrec, j + 0), r1 = __shfl(myrec, j + 1);
        int r2 = __shfl(myrec, j + 2), r3 = __shfl(myrec, j + 3);
        float4 w0 = gat4h(zzh, r0 & 0xffff, q);
        float4 w1 = gat4h(zzh, r1 & 0xffff, q);
        float4 w2 = gat4h(zzh, r2 & 0xffff, q);
        float4 w3 = gat4h(zzh, r3 & 0xffff, q);
        float n0 = rec_w(r0), n1 = rec_w(r1), n2 = rec_w(r2), n3 = rec_w(r3);
        a0 += n0 * w0.x + n1 * w1.x + n2 * w2.x + n3 * w3.x;
        a1 += n0 * w0.y + n1 * w1.y + n2 * w2.y + n3 * w3.y;
        a2 += n0 * w0.z + n1 * w1.z + n2 * w2.z + n3 * w3.z;
        a3 += n0 * w0.w + n1 * w1.w + n2 * w2.w + n3 * w3.w;
    }
    int done = c16 + ((v - c16) & 8);
    for (int j = done + half; j < v; j += 2) {
        int rr = __shfl(myrec, j);
        float nm = rec_w(rr);
        float4 w = gat4h(zzh, rr & 0xffff, q);
        a0 += nm * w.x; a1 += nm * w.y; a2 += nm * w.z; a3 += nm * w.w;
    }
    for (int e = e0 + 64 + half; e < e1; e += 2) {   // rare deg>64 overflow
        int rr = ebuf2[e];
        float nm = rec_w(rr);
        float4 w = gat4h(zzh, rr & 0xffff, q);
        a0 += nm * w.x; a1 += nm * w.y; a2 += nm * w.z; a3 += nm * w.w;
    }
    a0 += __shfl_xor(a0, 32);
    a1 += __shfl_xor(a1, 32);
    a2 += __shfl_xor(a2, 32);
    a3 += __shfl_xor(a3, 32);

    if (half == 0) {
        float4 b = *(const float4*)(bias + q * 4);
        float4 o;
        o.x = di * a0 + b.x;
        o.y = di * a1 + b.y;
        o.z = di * a2 + b.z;
        o.w = di * a3 + b.w;
        *(float4*)(out + (size_t)i * 128 + q * 4) = o;
    }
}

// ---------- pooling (hierarchical; h2 fp16) ----------
__global__ __launch_bounds__(128) void pool2_k(const __half* __restrict__ h2,
                                               const int* __restrict__ batch,
                                               float* __restrict__ pooled)
{
    int g = blockIdx.x;
    int c = blockIdx.y;
    int f = threadIdx.x;
    int bs = lowerb(batch, NN, g);
    int be = lowerb(batch, NN, g + 1);
    int len = be - bs;
    int cs = bs + (int)(((long long)len * c) / PCH);
    int ce = bs + (int)(((long long)len * (c + 1)) / PCH);
    float a = 0.f;
    for (int i = cs; i < ce; i++) a += __half2float(h2[(size_t)i * 128 + f]);
    if (ce > cs) atomicAdd(&pooled[(size_t)g * 128 + f], a);
}

// ---------- fused fc + decoder + W3 transform (zz out fp16) ----------
__global__ __launch_bounds__(128) void fcdec_k(const float* __restrict__ pooled,
                                               const float* __restrict__ fcW,   // [128][64]
                                               const float* __restrict__ fcb,
                                               const float* __restrict__ decW,  // [64][128]
                                               const float* __restrict__ decb,
                                               const float* __restrict__ W3,    // [128][128]
                                               float* __restrict__ lat_out,
                                               __half* __restrict__ zzh)
{
    __shared__ float lat[64];
    __shared__ float zs[128];
    int g = blockIdx.x, c = threadIdx.x;
    if (c < 64) {
        const float* p = pooled + (size_t)g * 128;
        float a = fcb[c];
        #pragma unroll 8
        for (int k = 0; k < 128; k++) a = fmaf(p[k], fcW[(size_t)k * 64 + c], a);
        a = fmaxf(a, 0.f);
        lat[c] = a;
        lat_out[(size_t)g * 64 + c] = a;
    }
    __syncthreads();
    {
        float a = decb[c];
        #pragma unroll 8
        for (int k = 0; k < 64; k++) a = fmaf(lat[k], decW[(size_t)k * 128 + c], a);
        zs[c] = fmaxf(a, 0.f);
    }
    __syncthreads();
    float o = 0.f;
    #pragma unroll 8
    for (int k = 0; k < 128; k++) o = fmaf(zs[k], W3[(size_t)k * 128 + c], o);
    zzh[(size_t)g * 128 + c] = __float2half(o);
}

extern "C" void kernel_launch(void* const* d_in, const int* in_sizes, int n_in,
                              void* d_out, int out_size, void* d_ws, size_t ws_size,
                              hipStream_t stream)
{
    const float* x     = (const float*)d_in[0];
    const int*   ei    = (const int*)d_in[1];
    const int*   batch = (const int*)d_in[2];
    const float* W1  = (const float*)d_in[3];
    const float* b1  = (const float*)d_in[4];
    const float* W2  = (const float*)d_in[5];
    const float* b2  = (const float*)d_in[6];
    const float* fcW = (const float*)d_in[7];
    const float* fcb = (const float*)d_in[8];
    const float* decW= (const float*)d_in[9];
    const float* decb= (const float*)d_in[10];
    const float* W3  = (const float*)d_in[11];
    const float* b3  = (const float*)d_in[12];

    char* ws = (char*)d_ws;
    size_t off = 0;
    auto alloc = [&](size_t bytes) -> char* {
        char* p = ws + off;
        off = (off + bytes + 255) & ~(size_t)255;
        return p;
    };
    float* dinv     = (float*)alloc((size_t)NN * 4);
    int*   rowptr   = (int*)alloc((size_t)(NN + 1) * 4);
    int*   bcur     = (int*)alloc((size_t)NB * 4);
    int*   ebuf     = (int*)alloc((size_t)EE * 4);           // CSR src indices (4B/edge)
    int*   ebuf2    = (int*)alloc((size_t)EE * 4);           // packed {bg | f16(dinv)<<16}
    float* pooled   = (float*)alloc((size_t)GG * 128 * 4);
    __half* zzh     = (__half*)alloc((size_t)GG * 128 * 2);  // decoded+W3 rows (fp16)
    f16x8* whi1     = (f16x8*)alloc(2048 * 16);              // W1 hi frags (32KB)
    f16x8* wlo1     = (f16x8*)alloc(2048 * 16);
    f16x8* whi2     = (f16x8*)alloc(2048 * 16);
    f16x8* wlo2     = (f16x8*)alloc(2048 * 16);
    __half* A       = (__half*)alloc((size_t)NN * 128 * 2);  // transformed feats (fp16)
    __half* B       = (__half*)alloc((size_t)NN * 128 * 2);  // h1/h2 activations (fp16)
    int2*  eraw     = (int2*)alloc((size_t)NB * CAP * 8);    // binA output

    float* recon_out = (float*)d_out;
    float* lat_out   = (float*)d_out + (size_t)NN * 128;

    prep_k<<<19, 256, 0, stream>>>(W1, W2, whi1, wlo1, whi2, wlo2, bcur, pooled);
    // gemm1 (unscaled t1 = x@W1) runs CONCURRENTLY with binA in one launch
    gemm1_binA_k<<<GBLK + ABLK, 512, 0, stream>>>(x, whi1, wlo1, A, ei, bcur, eraw);
    binB_k<<<NB, 512, 0, stream>>>(eraw, bcur, rowptr, dinv, ebuf);

    // conv1: h1 = relu(di*(sum dinv[s]*t[s] + di*t[i]) + b1) -> B (fp16); +pbb piggyback
    agghw_k<<<NN + PBBB, 64, 0, stream>>>(A, rowptr, ebuf, dinv, b1, B, batch, ebuf2);
    // conv2: pre-scaled fp16 GEMM (2 MFMAs/tile) + proven unweighted aggregation
    gemm_mfma2h_k<<<GBLK, 512, 0, stream>>>(B, whi2, wlo2, dinv, A, NN);
    aggh_k<<<NN, 64, 0, stream>>>(A, rowptr, ebuf, dinv, b2, B, batch, ebuf2);
    // pool + fused fc/dec (latent out, fp16 zz) + conv3
    pool2_k<<<dim3(GG, PCH), 128, 0, stream>>>(B, batch, pooled);
    fcdec_k<<<GG, 128, 0, stream>>>(pooled, fcW, fcb, decW, decb, W3, lat_out, zzh);
    agg_out_k<<<NN, 64, 0, stream>>>(zzh, batch, rowptr, ebuf2, dinv,
                                     b3, recon_out);
}